// Round 6
// baseline (411.563 us; speedup 1.0000x reference)
//
#include <hip/hip_runtime.h>

#define N_NODES 20000
#define N_EDGES 320000
#define HD 128
#define FIN 162      // 24 + 10 + 128
#define KE 260       // 2*H + ETN
#define KPAD 288     // 9 chunks of 32 (256..259 = edge-type, rest zero)

typedef unsigned short u16;
typedef __attribute__((ext_vector_type(8))) short bf16x8;
typedef __attribute__((ext_vector_type(4))) float f32x4;

__device__ __forceinline__ float leaky(float x){ return x > 0.f ? x : 0.01f*x; }
__device__ __forceinline__ unsigned fmap(float f){
    unsigned u = __float_as_uint(f);
    return (u & 0x80000000u) ? ~u : (u | 0x80000000u);
}
__device__ __forceinline__ float funmap(unsigned u){
    return __uint_as_float((u & 0x80000000u) ? (u & 0x7fffffffu) : ~u);
}
__device__ __forceinline__ unsigned umax_(unsigned a, unsigned b){ return a > b ? a : b; }
__device__ __forceinline__ u16 f2bf(float x){
    unsigned b = __float_as_uint(x);
    return (u16)((b + 0x7fffu + ((b >> 16) & 1u)) >> 16);
}
__device__ __forceinline__ float bf2f(u16 u){
    return __uint_as_float(((unsigned)u) << 16);
}

// ---------------------------------------------------------------------------
// device bodies for the fused front launch
// ---------------------------------------------------------------------------
__device__ void conv_w_dev(const float* __restrict__ w, u16* __restrict__ Wb, int layer)
{
    const float* src = w + (size_t)layer * 128 * KE;
    u16* dst = Wb + (size_t)layer * 128 * KPAD;
    for (int i = threadIdx.x; i < 128 * KPAD; i += 256) {
        int h = i / KPAD, k = i - h * KPAD;
        dst[i] = (k < KE) ? f2bf(src[h * KE + k]) : (u16)0;
    }
}

// cf = bf16((child_feats @ op_w.T + op_b) * exists) ; ipf0_m = mapped colmax
__device__ void encode_dev(char* sh, int bx,
    const float* __restrict__ feats, const float* __restrict__ exists,
    const float* __restrict__ W, const float* __restrict__ bvec,
    u16* __restrict__ cf, unsigned* __restrict__ ipf0_m)
{
    float (*As)[128]  = (float(*)[128])(sh);          // 16x128
    float (*Bs)[128]  = (float(*)[128])(sh + 8192);   // 16x128
    float (*As2)[128] = (float(*)[128])(sh + 16384);  // 2x128
    float (*Bs2)[128] = (float(*)[128])(sh + 17408);  // 2x128
    float* ex_s       = (float*)(sh + 18432);         // 128
    unsigned* colmax  = (unsigned*)(sh + 18944);      // 128

    const int t  = threadIdx.x;
    const int tx = t & 15, ty = t >> 4;
    const int base = bx * 128;

    if (t < 128) {
        int n = base + t; if (n >= N_NODES) n = N_NODES - 1;
        ex_s[t] = exists[n];
        colmax[t] = 0u;
        float2 v = *(const float2*)&feats[n*FIN + 160];
        As2[0][t] = v.x; As2[1][t] = v.y;
        float2 w = *(const float2*)&W[t*FIN + 160];
        Bs2[0][t] = w.x; Bs2[1][t] = w.y;
    }

    float acc[8][8];
    #pragma unroll
    for (int i = 0; i < 8; ++i)
        #pragma unroll
        for (int j = 0; j < 8; ++j) acc[i][j] = 0.f;

    for (int c = 0; c < 10; ++c) {
        const int kk = c * 16;
        __syncthreads();
        #pragma unroll
        for (int l = 0; l < 4; ++l) {
            int idx = l*256 + t;
            int m = idx & 127, kh = idx >> 7;
            int n = base + m; if (n >= N_NODES) n = N_NODES - 1;
            float2 v = *(const float2*)&feats[n*FIN + kk + kh*2];
            As[kh*2+0][m] = v.x; As[kh*2+1][m] = v.y;
        }
        #pragma unroll
        for (int l = 0; l < 4; ++l) {
            int idx = l*256 + t;
            int h = idx & 127, kh = idx >> 7;
            float2 v = *(const float2*)&W[h*FIN + kk + kh*2];
            Bs[kh*2+0][h] = v.x; Bs[kh*2+1][h] = v.y;
        }
        __syncthreads();
        #pragma unroll
        for (int k = 0; k < 16; ++k) {
            float4 a0 = *(const float4*)&As[k][ty*8];
            float4 a1 = *(const float4*)&As[k][ty*8+4];
            float4 b0 = *(const float4*)&Bs[k][tx*8];
            float4 b1 = *(const float4*)&Bs[k][tx*8+4];
            float av[8] = {a0.x,a0.y,a0.z,a0.w,a1.x,a1.y,a1.z,a1.w};
            float bv[8] = {b0.x,b0.y,b0.z,b0.w,b1.x,b1.y,b1.z,b1.w};
            #pragma unroll
            for (int i = 0; i < 8; ++i)
                #pragma unroll
                for (int j = 0; j < 8; ++j)
                    acc[i][j] = fmaf(av[i], bv[j], acc[i][j]);
        }
    }
    #pragma unroll
    for (int k = 0; k < 2; ++k) {
        float av[8], bv[8];
        #pragma unroll
        for (int i = 0; i < 8; ++i) av[i] = As2[k][ty*8+i];
        #pragma unroll
        for (int j = 0; j < 8; ++j) bv[j] = Bs2[k][tx*8+j];
        #pragma unroll
        for (int i = 0; i < 8; ++i)
            #pragma unroll
            for (int j = 0; j < 8; ++j)
                acc[i][j] = fmaf(av[i], bv[j], acc[i][j]);
    }

    float bias8[8];
    #pragma unroll
    for (int j = 0; j < 8; ++j) bias8[j] = bvec[tx*8+j];

    #pragma unroll
    for (int i = 0; i < 8; ++i) {
        int m = ty*8 + i; int n = base + m;
        float ex = ex_s[m];
        #pragma unroll
        for (int j = 0; j < 8; ++j) acc[i][j] = (acc[i][j] + bias8[j]) * ex;
        if (n < N_NODES) {
            union { u16 us[8]; uint4 v; } pk;
            #pragma unroll
            for (int j = 0; j < 8; ++j) pk.us[j] = f2bf(acc[i][j]);
            *(uint4*)&cf[n*HD + tx*8] = pk.v;
        }
    }
    #pragma unroll
    for (int j = 0; j < 8; ++j) {
        unsigned mx = 0u;
        #pragma unroll
        for (int i = 0; i < 8; ++i) mx = umax_(mx, fmap(acc[i][j]));
        atomicMax(&colmax[tx*8+j], mx);
    }
    __syncthreads();
    if (t < 128) atomicMax(&ipf0_m[t], colmax[t]);
}

// colmax of (geo @ Wy.T + by) * exists for y in {child_geo, skip}
__device__ void geo_dev(char* sh, int bx, int which,
    const float* __restrict__ feats, const float* __restrict__ exists,
    const float* __restrict__ W0, const float* __restrict__ b0,
    const float* __restrict__ W1, const float* __restrict__ b1,
    unsigned* __restrict__ acc0, unsigned* __restrict__ acc1)
{
    const float* W  = which ? W1 : W0;
    const float* bv = which ? b1 : b0;
    unsigned* accout = which ? acc1 : acc0;

    float (*As)[128] = (float(*)[128])(sh);          // 16x128
    float (*Bs)[128] = (float(*)[128])(sh + 8192);   // 16x128
    float* ex_s      = (float*)(sh + 16384);
    unsigned* colmax = (unsigned*)(sh + 16896);

    const int t  = threadIdx.x;
    const int tx = t & 15, ty = t >> 4;
    const int base = bx * 128;

    if (t < 128) {
        int n = base + t; if (n >= N_NODES) n = N_NODES - 1;
        ex_s[t] = exists[n];
        colmax[t] = 0u;
    }
    float acc[8][8];
    #pragma unroll
    for (int i = 0; i < 8; ++i)
        #pragma unroll
        for (int j = 0; j < 8; ++j) acc[i][j] = 0.f;

    for (int c = 0; c < 8; ++c) {
        const int kk = c * 16;
        __syncthreads();
        #pragma unroll
        for (int l = 0; l < 2; ++l) {
            int idx = l*256 + t;
            int m = idx & 127, kq = idx >> 7;
            int n = base + m; if (n >= N_NODES) n = N_NODES - 1;
            float4 v = *(const float4*)&feats[n*HD + kk + kq*4];
            As[kq*4+0][m]=v.x; As[kq*4+1][m]=v.y; As[kq*4+2][m]=v.z; As[kq*4+3][m]=v.w;
        }
        #pragma unroll
        for (int l = 0; l < 2; ++l) {
            int idx = l*256 + t;
            int h = idx & 127, kq = idx >> 7;
            float4 v = *(const float4*)&W[h*HD + kk + kq*4];
            Bs[kq*4+0][h]=v.x; Bs[kq*4+1][h]=v.y; Bs[kq*4+2][h]=v.z; Bs[kq*4+3][h]=v.w;
        }
        __syncthreads();
        #pragma unroll
        for (int k = 0; k < 16; ++k) {
            float4 a0 = *(const float4*)&As[k][ty*8];
            float4 a1 = *(const float4*)&As[k][ty*8+4];
            float4 b0 = *(const float4*)&Bs[k][tx*8];
            float4 b1 = *(const float4*)&Bs[k][tx*8+4];
            float av[8] = {a0.x,a0.y,a0.z,a0.w,a1.x,a1.y,a1.z,a1.w};
            float bvv[8] = {b0.x,b0.y,b0.z,b0.w,b1.x,b1.y,b1.z,b1.w};
            #pragma unroll
            for (int i = 0; i < 8; ++i)
                #pragma unroll
                for (int j = 0; j < 8; ++j)
                    acc[i][j] = fmaf(av[i], bvv[j], acc[i][j]);
        }
    }

    float bias8[8];
    #pragma unroll
    for (int j = 0; j < 8; ++j) bias8[j] = bv[tx*8+j];
    #pragma unroll
    for (int j = 0; j < 8; ++j) {
        unsigned mx = 0u;
        #pragma unroll
        for (int i = 0; i < 8; ++i) {
            float v = (acc[i][j] + bias8[j]) * ex_s[ty*8+i];
            mx = umax_(mx, fmap(v));
        }
        atomicMax(&colmax[tx*8+j], mx);
    }
    __syncthreads();
    if (t < 128) atomicMax(&accout[t], colmax[t]);
}

// fused: [0,2) conv_w | [2,1252) from-histogram | [1252,1409) encode | [1409,1723) geo
__global__ __launch_bounds__(256) void fused_front(
    const float* __restrict__ edge_w, u16* __restrict__ Wb,
    const int* __restrict__ eidx, int* __restrict__ count,
    const float* __restrict__ child_feats, const float* __restrict__ child_exists,
    const float* __restrict__ op_w, const float* __restrict__ op_b,
    u16* __restrict__ cf_a, unsigned* __restrict__ ipf0_m,
    const float* __restrict__ child_geo,
    const float* __restrict__ geo_w, const float* __restrict__ geo_b,
    const float* __restrict__ skip_w, const float* __restrict__ skip_b,
    unsigned* __restrict__ pg_m, unsigned* __restrict__ sg_m)
{
    __shared__ __align__(16) char sh[19456];
    const int b = blockIdx.x;
    if (b < 2) {
        conv_w_dev(edge_w, Wb, b);
    } else if (b < 1252) {
        int e = (b - 2) * 256 + threadIdx.x;
        atomicAdd(&count[eidx[2*e]], 1);
    } else if (b < 1409) {
        encode_dev(sh, b - 1252, child_feats, child_exists, op_w, op_b, cf_a, ipf0_m);
    } else {
        int g = b - 1409;
        int which = (g >= 157) ? 1 : 0;
        geo_dev(sh, which ? g - 157 : g, which,
                child_geo, child_exists, geo_w, geo_b, skip_w, skip_b, pg_m, sg_m);
    }
}

// ---------------------------------------------------------------------------
__global__ __launch_bounds__(1024) void scan_offsets(
    const int* __restrict__ count, int* __restrict__ offset)
{
    __shared__ int part[1024];
    const int t = threadIdx.x;
    const int lo = t * 20;
    const int hi = min(lo + 20, N_NODES);
    int s = 0;
    for (int n = lo; n < hi; ++n) s += count[n];
    part[t] = s;
    __syncthreads();
    for (int d = 1; d < 1024; d <<= 1) {
        int v = (t >= d) ? part[t - d] : 0;
        __syncthreads();
        part[t] += v;
        __syncthreads();
    }
    int run = (t > 0) ? part[t - 1] : 0;
    for (int n = lo; n < hi; ++n) { offset[n] = run; run += count[n]; }
}

// fill permuted edge arrays in CSR (from-sorted) order
__global__ __launch_bounds__(256) void fill_perm(
    const int* __restrict__ eidx, const float* __restrict__ ef,
    const int* __restrict__ offset, int* __restrict__ cursor,
    int* __restrict__ from_p, int* __restrict__ to_p, uint2* __restrict__ efb_p)
{
    int e = blockIdx.x * 256 + threadIdx.x;
    int2 p = ((const int2*)eidx)[e];
    int pos = offset[p.x] + atomicAdd(&cursor[p.x], 1);
    from_p[pos] = p.x; to_p[pos] = p.y;
    float4 e4 = ((const float4*)ef)[e];
    efb_p[pos] = make_uint2(
        (unsigned)f2bf(e4.x) | ((unsigned)f2bf(e4.y) << 16),
        (unsigned)f2bf(e4.z) | ((unsigned)f2bf(e4.w) << 16));
}

// ---------------------------------------------------------------------------
// MFMA edge pass on CSR-permuted edges: msg = leaky([cf[f]|cf[t]|ef]@W.T + b)
// 256 edges x 128 ch per block; 8 waves in 4x2 grid (64x64 each); K = 9x32
// REDUCE: in-register segmax -- each wave covers 64 CSR-contiguous rows;
//   per-node max via predicated lane maxes + quad butterflies. Interior nodes
//   (range fully inside the wave's 64 rows) get plain fp32 stores; boundary
//   nodes get int-bits atomicMax (values >= 0, init 0). No msgb materialized.
// ---------------------------------------------------------------------------
template<int REDUCE>
__global__ __launch_bounds__(512, 4) void edge_mfma(
    const u16* __restrict__ cfb,       // [N,128] bf16 (gather source)
    const int* __restrict__ from_p,    // [E] sorted
    const int* __restrict__ to_p,      // [E] permuted
    const uint2* __restrict__ efb_p,   // [E] 4x bf16 packed
    const u16* __restrict__ Wb,        // [128,288] bf16 (padded)
    const float* __restrict__ bias,    // [128]
    const int* __restrict__ offs,      // [N] CSR offsets
    const int* __restrict__ cnt,       // [N] degrees
    float* __restrict__ cf_out,        // [N,128] fp32 scatter-max (init 0)
    int* __restrict__ ipf_out)         // [128]
{
    __shared__ __align__(16) u16 smem[24576];   // 49152 B
    __shared__ int colmax_s[128];

    const int t    = threadIdx.x;
    const int base = blockIdx.x * 256;          // 1250 blocks exact
    const int wave = t >> 6, l = t & 63;
    const int quad = l >> 4, lc = l & 15;
    const int R0 = (wave >> 1) * 64;
    const int C0 = (wave & 1) * 64;
    const bool isA = (t < 256);

    int nf = 0, nt2 = 0; uint2 efr = make_uint2(0, 0);
    if (isA) {
        nf  = from_p[base + t];
        nt2 = to_p[base + t];
        efr = efb_p[base + t];
    }
    if (t < 128) colmax_s[t] = 0;

    uint4 pref[4];
    auto prefetch = [&](int c) {
        if (isA) {
            if (c < 8) {
                int node = (c < 4) ? nf : nt2;
                const uint4* src = (const uint4*)(cfb + node * HD + (c & 3) * 32);
                pref[0] = src[0]; pref[1] = src[1]; pref[2] = src[2]; pref[3] = src[3];
            } else {
                pref[0] = make_uint4(efr.x, efr.y, 0u, 0u);
                pref[1] = make_uint4(0,0,0,0);
                pref[2] = make_uint4(0,0,0,0);
                pref[3] = make_uint4(0,0,0,0);
            }
        } else {
            int row = (t - 256) >> 1;
            const uint4* src = (const uint4*)(Wb + row * KPAD + c * 32) + (t & 1) * 2;
            pref[0] = src[0]; pref[1] = src[1];
        }
    };
    auto commit = [&](int c) {
        if (isA) {
            u16* dst = smem + (c & 1) * 8192 + t * 32;
            *(uint4*)(dst +  0) = pref[0];
            *(uint4*)(dst +  8) = pref[1];
            *(uint4*)(dst + 16) = pref[2];
            *(uint4*)(dst + 24) = pref[3];
        } else {
            int row = (t - 256) >> 1;
            u16* dst = smem + 16384 + (c & 1) * 4096 + row * 32 + (t & 1) * 16;
            *(uint4*)(dst + 0) = pref[0];
            *(uint4*)(dst + 8) = pref[1];
        }
    };

    prefetch(0); commit(0);
    __syncthreads();

    f32x4 acc[4][4];
    #pragma unroll
    for (int i = 0; i < 4; ++i)
        #pragma unroll
        for (int j = 0; j < 4; ++j) acc[i][j] = (f32x4){0.f, 0.f, 0.f, 0.f};

    for (int c = 0; c < 9; ++c) {
        if (c < 8) prefetch(c + 1);
        const u16* Ab = smem + (c & 1) * 8192 + (R0 + lc) * 32 + quad * 8;
        const u16* Bb = smem + 16384 + (c & 1) * 4096 + (C0 + lc) * 32 + quad * 8;
        bf16x8 af[4], bfr[4];
        #pragma unroll
        for (int ti = 0; ti < 4; ++ti) af[ti]  = *(const bf16x8*)(Ab + ti * 16 * 32);
        #pragma unroll
        for (int tj = 0; tj < 4; ++tj) bfr[tj] = *(const bf16x8*)(Bb + tj * 16 * 32);
        #pragma unroll
        for (int ti = 0; ti < 4; ++ti)
            #pragma unroll
            for (int tj = 0; tj < 4; ++tj)
                acc[ti][tj] = __builtin_amdgcn_mfma_f32_16x16x32_bf16(
                    af[ti], bfr[tj], acc[ti][tj], 0, 0, 0);
        if (c < 8) { commit(c + 1); __syncthreads(); }
    }

    // bias + leaky in-place; per-channel block max
    #pragma unroll
    for (int tj = 0; tj < 4; ++tj) {
        const int col = C0 + tj * 16 + lc;
        const float bc = bias[col];
        float mx = 0.f;
        #pragma unroll
        for (int ti = 0; ti < 4; ++ti) {
            #pragma unroll
            for (int r = 0; r < 4; ++r) {
                float x = leaky(acc[ti][tj][r] + bc);
                acc[ti][tj][r] = x;
                mx = fmaxf(mx, x);
            }
        }
        atomicMax(&colmax_s[col], __float_as_int(mx));   // mx >= 0: int-bits OK
    }

    if (REDUCE) {
        // in-register per-from-node scatter max over this wave's 64 rows
        const int rowbase = base + R0;
        int myfrom = from_p[rowbase + l];       // sorted
        int n0 = __shfl(myfrom, 0);
        int n1 = __shfl(myfrom, 63);
        // pre-load offs/cnt for up to 64 nodes into lanes
        int idx = n0 + l;
        int oj = 0, cj = 0;
        if (idx <= n1) { oj = offs[idx]; cj = cnt[idx]; }
        for (int n = n0; n <= n1; ++n) {
            int d = n - n0;
            int o, c;
            if (d < 64) { o = __shfl(oj, d); c = __shfl(cj, d); }
            else { o = offs[n]; c = cnt[n]; }
            int lo = o - rowbase, hi = o + c - rowbase;
            int lo2 = lo > 0 ? lo : 0;
            int hi2 = hi < 64 ? hi : 64;
            if (lo2 >= hi2) continue;            // no rows here (incl deg-0)
            float mc[4] = {0.f, 0.f, 0.f, 0.f};  // 0 floor matches zeros.at[].max
            #pragma unroll
            for (int ti = 0; ti < 4; ++ti) {
                #pragma unroll
                for (int r = 0; r < 4; ++r) {
                    int row = ti * 16 + quad * 4 + r;
                    bool in = (row >= lo2) && (row < hi2);
                    #pragma unroll
                    for (int tj = 0; tj < 4; ++tj)
                        mc[tj] = in ? fmaxf(mc[tj], acc[ti][tj][r]) : mc[tj];
                }
            }
            bool interior = (lo >= 0) && (hi <= 64);
            #pragma unroll
            for (int tj = 0; tj < 4; ++tj) {
                float v = mc[tj];
                v = fmaxf(v, __shfl_xor(v, 16));
                v = fmaxf(v, __shfl_xor(v, 32));
                if (quad == 0) {
                    int col = C0 + tj * 16 + lc;
                    if (interior) cf_out[(size_t)n * HD + col] = v;
                    else atomicMax((int*)&cf_out[(size_t)n * HD + col],
                                   __float_as_int(v));
                }
            }
        }
    }

    __syncthreads();
    if (t < 128) atomicMax(&ipf_out[t], colmax_s[t]);
}

// ---------------------------------------------------------------------------
// cf_b32 fp32 -> bf16 (RTNE), vectorized
// ---------------------------------------------------------------------------
__global__ __launch_bounds__(256) void cvt_cf(
    const float* __restrict__ src, u16* __restrict__ dst)
{
    int i = blockIdx.x * 256 + threadIdx.x;      // one uint4 (8 bf16) each
    const float4* s = (const float4*)src + (size_t)i * 2;
    float4 a = s[0], b = s[1];
    union { u16 us[8]; uint4 v; } pk;
    pk.us[0] = f2bf(a.x); pk.us[1] = f2bf(a.y);
    pk.us[2] = f2bf(a.z); pk.us[3] = f2bf(a.w);
    pk.us[4] = f2bf(b.x); pk.us[5] = f2bf(b.y);
    pk.us[6] = f2bf(b.z); pk.us[7] = f2bf(b.w);
    ((uint4*)dst)[i] = pk.v;
}

// ---------------------------------------------------------------------------
// fused heads: block 0 = parent_feat, block 1 = parent_geo
// ---------------------------------------------------------------------------
__global__ __launch_bounds__(128) void heads(
    const unsigned* __restrict__ ipf0_m,
    const float* __restrict__ ipf1, const float* __restrict__ ipf2,
    const float* __restrict__ secW, const float* __restrict__ secB,
    const unsigned* __restrict__ pg_m, const unsigned* __restrict__ sg_m,
    const float* __restrict__ geoW, const float* __restrict__ geoB,
    const float* __restrict__ gnw, const float* __restrict__ gnb,
    float* __restrict__ out)
{
    const int t = threadIdx.x;
    if (blockIdx.x == 0) {
        __shared__ float s[384];
        s[t]       = funmap(ipf0_m[t]);
        s[128 + t] = ipf1[t];
        s[256 + t] = ipf2[t];
        __syncthreads();
        float acc = secB[t];
        #pragma unroll 4
        for (int k = 0; k < 384; ++k) acc = fmaf(s[k], secW[t*384 + k], acc);
        out[t] = leaky(acc);
    } else {
        __shared__ float pg[128];
        __shared__ float tt[128];
        pg[t] = leaky(funmap(pg_m[t]));
        float sg = leaky(funmap(sg_m[t]));
        __syncthreads();
        float acc = geoB[t];
        #pragma unroll 4
        for (int k = 0; k < 128; ++k) acc = fmaf(pg[k], geoW[t*128 + k], acc);
        tt[t] = acc;
        __syncthreads();
        const int g = (t >> 3) << 3;
        float mu = 0.f, m2 = 0.f;
        #pragma unroll
        for (int q = 0; q < 8; ++q) { float x = tt[g + q]; mu += x; m2 += x*x; }
        mu *= 0.125f;
        m2 = m2 * 0.125f - mu * mu;
        float xn = (acc - mu) * rsqrtf(m2 + 1e-5f);
        out[128 + t] = leaky(sg + xn * gnw[t] + gnb[t]);
    }
}

// ---------------------------------------------------------------------------
extern "C" void kernel_launch(void* const* d_in, const int* in_sizes, int n_in,
                              void* d_out, int out_size, void* d_ws, size_t ws_size,
                              hipStream_t stream)
{
    const float* child_feats  = (const float*)d_in[0];
    const float* child_geo    = (const float*)d_in[1];
    const float* child_exists = (const float*)d_in[2];
    const float* etoh         = (const float*)d_in[3];
    const int*   eidx         = (const int*)  d_in[4];
    const float* op_w   = (const float*)d_in[5];
    const float* op_b   = (const float*)d_in[6];
    const float* sec_w  = (const float*)d_in[7];
    const float* sec_b  = (const float*)d_in[8];
    const float* edge_w = (const float*)d_in[9];
    const float* edge_b = (const float*)d_in[10];
    const float* geo_w  = (const float*)d_in[11];
    const float* geo_b  = (const float*)d_in[12];
    const float* sgeo_w = (const float*)d_in[13];
    const float* sgeo_b = (const float*)d_in[14];
    const float* gn_w   = (const float*)d_in[15];
    const float* gn_b   = (const float*)d_in[16];
    const float* skip_w = (const float*)d_in[17];
    const float* skip_b = (const float*)d_in[18];
    float* out = (float*)d_out;

    // workspace layout (all offsets 16B aligned)
    char* ws = (char*)d_ws;
    size_t off = 0;
    u16*   cf_a   = (u16*)(ws + off);   off += (size_t)N_NODES*HD*2;    // 5.12 MB
    u16*   cf_bb  = (u16*)(ws + off);   off += (size_t)N_NODES*HD*2;    // 5.12 MB (bf16 cf_b)
    u16*   Wb     = (u16*)(ws + off);   off += (size_t)2*128*KPAD*2;    // 147 KB
    int*   from_p = (int*)(ws + off);   off += (size_t)N_EDGES*4;       // 1.28 MB
    int*   to_p   = (int*)(ws + off);   off += (size_t)N_EDGES*4;       // 1.28 MB
    uint2* efb_p  = (uint2*)(ws + off); off += (size_t)N_EDGES*8;       // 2.56 MB
    int*   offs   = (int*)(ws + off);   off += (size_t)N_NODES*4;       // 80 KB
    char*  zero0  = ws + off;
    float* cf_b32 = (float*)(ws + off);       off += (size_t)N_NODES*HD*4;  // 10.24 MB
    unsigned* ipf0_m = (unsigned*)(ws + off); off += 128*4;
    float*    ipf1   = (float*)(ws + off);    off += 128*4;
    float*    ipf2   = (float*)(ws + off);    off += 128*4;
    unsigned* pg_m   = (unsigned*)(ws + off); off += 128*4;
    unsigned* sg_m   = (unsigned*)(ws + off); off += 128*4;
    int*      count  = (int*)(ws + off);      off += (size_t)N_NODES*4;
    int*      cursor = (int*)(ws + off);      off += (size_t)N_NODES*4;
    size_t zero_bytes = (size_t)(ws + off - zero0);

    hipMemsetAsync(zero0, 0, zero_bytes, stream);

    // conv_w + histogram + encode + geo in one launch
    fused_front<<<1723, 256, 0, stream>>>(
        edge_w, Wb, eidx, count,
        child_feats, child_exists, op_w, op_b, cf_a, ipf0_m,
        child_geo, geo_w, geo_b, skip_w, skip_b, pg_m, sg_m);

    scan_offsets<<<1, 1024, 0, stream>>>(count, offs);

    fill_perm<<<N_EDGES/256, 256, 0, stream>>>(
        eidx, etoh, offs, cursor, from_p, to_p, efb_p);

    // iter 1: MFMA messages + fused in-register scatter-max -> cf_b32
    edge_mfma<1><<<N_EDGES/256, 512, 0, stream>>>(
        cf_a, from_p, to_p, efb_p, Wb, edge_b,
        offs, count, cf_b32, (int*)ipf1);

    // fp32 -> bf16 for pass-2 gather
    cvt_cf<<<(N_NODES*HD/8)/256, 256, 0, stream>>>(cf_b32, cf_bb);

    // iter 2: only column max needed
    edge_mfma<0><<<N_EDGES/256, 512, 0, stream>>>(
        cf_bb, from_p, to_p, efb_p, Wb + 128*KPAD, edge_b + 128,
        offs, count, nullptr, (int*)ipf2);

    heads<<<2, 128, 0, stream>>>(ipf0_m, ipf1, ipf2, sec_w, sec_b,
                                 pg_m, sg_m, sgeo_w, sgeo_b, gn_w, gn_b, out);
}

// Round 7
// 353.130 us; speedup vs baseline: 1.1655x; 1.1655x over previous
//
#include <hip/hip_runtime.h>

#define N_NODES 20000
#define N_EDGES 320000
#define HD 128
#define FIN 162      // 24 + 10 + 128
#define KE 260       // 2*H + ETN
#define KPAD 288     // 9 chunks of 32 (256..259 = edge-type, rest zero)
#define WSTR 296     // LDS row stride for W (u16): 592 B, 16B-aligned
#define TSTR 136     // transpose-buffer row stride (u16): 272 B

typedef unsigned short u16;
typedef __attribute__((ext_vector_type(8))) short bf16x8;
typedef __attribute__((ext_vector_type(4))) float f32x4;

__device__ __forceinline__ float leaky(float x){ return x > 0.f ? x : 0.01f*x; }
__device__ __forceinline__ unsigned fmap(float f){
    unsigned u = __float_as_uint(f);
    return (u & 0x80000000u) ? ~u : (u | 0x80000000u);
}
__device__ __forceinline__ float funmap(unsigned u){
    return __uint_as_float((u & 0x80000000u) ? (u & 0x7fffffffu) : ~u);
}
__device__ __forceinline__ unsigned umax_(unsigned a, unsigned b){ return a > b ? a : b; }
__device__ __forceinline__ u16 f2bf(float x){
    unsigned b = __float_as_uint(x);
    return (u16)((b + 0x7fffu + ((b >> 16) & 1u)) >> 16);
}
__device__ __forceinline__ float bf2f(u16 u){
    return __uint_as_float(((unsigned)u) << 16);
}

// ---------------------------------------------------------------------------
// device bodies for the fused front launch
// ---------------------------------------------------------------------------
__device__ void conv_w_dev(const float* __restrict__ w, u16* __restrict__ Wb, int layer)
{
    const float* src = w + (size_t)layer * 128 * KE;
    u16* dst = Wb + (size_t)layer * 128 * KPAD;
    for (int i = threadIdx.x; i < 128 * KPAD; i += 256) {
        int h = i / KPAD, k = i - h * KPAD;
        dst[i] = (k < KE) ? f2bf(src[h * KE + k]) : (u16)0;
    }
}

// cf = bf16((child_feats @ op_w.T + op_b) * exists) ; ipf0_m = mapped colmax
__device__ void encode_dev(char* sh, int bx,
    const float* __restrict__ feats, const float* __restrict__ exists,
    const float* __restrict__ W, const float* __restrict__ bvec,
    u16* __restrict__ cf, unsigned* __restrict__ ipf0_m)
{
    float (*As)[128]  = (float(*)[128])(sh);          // 16x128
    float (*Bs)[128]  = (float(*)[128])(sh + 8192);   // 16x128
    float (*As2)[128] = (float(*)[128])(sh + 16384);  // 2x128
    float (*Bs2)[128] = (float(*)[128])(sh + 17408);  // 2x128
    float* ex_s       = (float*)(sh + 18432);         // 128
    unsigned* colmax  = (unsigned*)(sh + 18944);      // 128

    const int t  = threadIdx.x;
    const int tx = t & 15, ty = t >> 4;
    const int base = bx * 128;

    if (t < 128) {
        int n = base + t; if (n >= N_NODES) n = N_NODES - 1;
        ex_s[t] = exists[n];
        colmax[t] = 0u;
        float2 v = *(const float2*)&feats[n*FIN + 160];
        As2[0][t] = v.x; As2[1][t] = v.y;
        float2 w = *(const float2*)&W[t*FIN + 160];
        Bs2[0][t] = w.x; Bs2[1][t] = w.y;
    }

    float acc[8][8];
    #pragma unroll
    for (int i = 0; i < 8; ++i)
        #pragma unroll
        for (int j = 0; j < 8; ++j) acc[i][j] = 0.f;

    for (int c = 0; c < 10; ++c) {
        const int kk = c * 16;
        __syncthreads();
        #pragma unroll
        for (int l = 0; l < 4; ++l) {
            int idx = l*256 + t;
            int m = idx & 127, kh = idx >> 7;
            int n = base + m; if (n >= N_NODES) n = N_NODES - 1;
            float2 v = *(const float2*)&feats[n*FIN + kk + kh*2];
            As[kh*2+0][m] = v.x; As[kh*2+1][m] = v.y;
        }
        #pragma unroll
        for (int l = 0; l < 4; ++l) {
            int idx = l*256 + t;
            int h = idx & 127, kh = idx >> 7;
            float2 v = *(const float2*)&W[h*FIN + kk + kh*2];
            Bs[kh*2+0][h] = v.x; Bs[kh*2+1][h] = v.y;
        }
        __syncthreads();
        #pragma unroll
        for (int k = 0; k < 16; ++k) {
            float4 a0 = *(const float4*)&As[k][ty*8];
            float4 a1 = *(const float4*)&As[k][ty*8+4];
            float4 b0 = *(const float4*)&Bs[k][tx*8];
            float4 b1 = *(const float4*)&Bs[k][tx*8+4];
            float av[8] = {a0.x,a0.y,a0.z,a0.w,a1.x,a1.y,a1.z,a1.w};
            float bv[8] = {b0.x,b0.y,b0.z,b0.w,b1.x,b1.y,b1.z,b1.w};
            #pragma unroll
            for (int i = 0; i < 8; ++i)
                #pragma unroll
                for (int j = 0; j < 8; ++j)
                    acc[i][j] = fmaf(av[i], bv[j], acc[i][j]);
        }
    }
    #pragma unroll
    for (int k = 0; k < 2; ++k) {
        float av[8], bv[8];
        #pragma unroll
        for (int i = 0; i < 8; ++i) av[i] = As2[k][ty*8+i];
        #pragma unroll
        for (int j = 0; j < 8; ++j) bv[j] = Bs2[k][tx*8+j];
        #pragma unroll
        for (int i = 0; i < 8; ++i)
            #pragma unroll
            for (int j = 0; j < 8; ++j)
                acc[i][j] = fmaf(av[i], bv[j], acc[i][j]);
    }

    float bias8[8];
    #pragma unroll
    for (int j = 0; j < 8; ++j) bias8[j] = bvec[tx*8+j];

    #pragma unroll
    for (int i = 0; i < 8; ++i) {
        int m = ty*8 + i; int n = base + m;
        float ex = ex_s[m];
        #pragma unroll
        for (int j = 0; j < 8; ++j) acc[i][j] = (acc[i][j] + bias8[j]) * ex;
        if (n < N_NODES) {
            union { u16 us[8]; uint4 v; } pk;
            #pragma unroll
            for (int j = 0; j < 8; ++j) pk.us[j] = f2bf(acc[i][j]);
            *(uint4*)&cf[n*HD + tx*8] = pk.v;
        }
    }
    #pragma unroll
    for (int j = 0; j < 8; ++j) {
        unsigned mx = 0u;
        #pragma unroll
        for (int i = 0; i < 8; ++i) mx = umax_(mx, fmap(acc[i][j]));
        atomicMax(&colmax[tx*8+j], mx);
    }
    __syncthreads();
    if (t < 128) atomicMax(&ipf0_m[t], colmax[t]);
}

// colmax of (geo @ Wy.T + by) * exists for y in {child_geo, skip}
__device__ void geo_dev(char* sh, int bx, int which,
    const float* __restrict__ feats, const float* __restrict__ exists,
    const float* __restrict__ W0, const float* __restrict__ b0,
    const float* __restrict__ W1, const float* __restrict__ b1,
    unsigned* __restrict__ acc0, unsigned* __restrict__ acc1)
{
    const float* W  = which ? W1 : W0;
    const float* bv = which ? b1 : b0;
    unsigned* accout = which ? acc1 : acc0;

    float (*As)[128] = (float(*)[128])(sh);          // 16x128
    float (*Bs)[128] = (float(*)[128])(sh + 8192);   // 16x128
    float* ex_s      = (float*)(sh + 16384);
    unsigned* colmax = (unsigned*)(sh + 16896);

    const int t  = threadIdx.x;
    const int tx = t & 15, ty = t >> 4;
    const int base = bx * 128;

    if (t < 128) {
        int n = base + t; if (n >= N_NODES) n = N_NODES - 1;
        ex_s[t] = exists[n];
        colmax[t] = 0u;
    }
    float acc[8][8];
    #pragma unroll
    for (int i = 0; i < 8; ++i)
        #pragma unroll
        for (int j = 0; j < 8; ++j) acc[i][j] = 0.f;

    for (int c = 0; c < 8; ++c) {
        const int kk = c * 16;
        __syncthreads();
        #pragma unroll
        for (int l = 0; l < 2; ++l) {
            int idx = l*256 + t;
            int m = idx & 127, kq = idx >> 7;
            int n = base + m; if (n >= N_NODES) n = N_NODES - 1;
            float4 v = *(const float4*)&feats[n*HD + kk + kq*4];
            As[kq*4+0][m]=v.x; As[kq*4+1][m]=v.y; As[kq*4+2][m]=v.z; As[kq*4+3][m]=v.w;
        }
        #pragma unroll
        for (int l = 0; l < 2; ++l) {
            int idx = l*256 + t;
            int h = idx & 127, kq = idx >> 7;
            float4 v = *(const float4*)&W[h*HD + kk + kq*4];
            Bs[kq*4+0][h]=v.x; Bs[kq*4+1][h]=v.y; Bs[kq*4+2][h]=v.z; Bs[kq*4+3][h]=v.w;
        }
        __syncthreads();
        #pragma unroll
        for (int k = 0; k < 16; ++k) {
            float4 a0 = *(const float4*)&As[k][ty*8];
            float4 a1 = *(const float4*)&As[k][ty*8+4];
            float4 b0 = *(const float4*)&Bs[k][tx*8];
            float4 b1 = *(const float4*)&Bs[k][tx*8+4];
            float av[8] = {a0.x,a0.y,a0.z,a0.w,a1.x,a1.y,a1.z,a1.w};
            float bvv[8] = {b0.x,b0.y,b0.z,b0.w,b1.x,b1.y,b1.z,b1.w};
            #pragma unroll
            for (int i = 0; i < 8; ++i)
                #pragma unroll
                for (int j = 0; j < 8; ++j)
                    acc[i][j] = fmaf(av[i], bvv[j], acc[i][j]);
        }
    }

    float bias8[8];
    #pragma unroll
    for (int j = 0; j < 8; ++j) bias8[j] = bv[tx*8+j];
    #pragma unroll
    for (int j = 0; j < 8; ++j) {
        unsigned mx = 0u;
        #pragma unroll
        for (int i = 0; i < 8; ++i) {
            float v = (acc[i][j] + bias8[j]) * ex_s[ty*8+i];
            mx = umax_(mx, fmap(v));
        }
        atomicMax(&colmax[tx*8+j], mx);
    }
    __syncthreads();
    if (t < 128) atomicMax(&accout[t], colmax[t]);
}

// fused: [0,2) conv_w | [2,1252) from-histogram | [1252,1409) encode | [1409,1723) geo
__global__ __launch_bounds__(256) void fused_front(
    const float* __restrict__ edge_w, u16* __restrict__ Wb,
    const int* __restrict__ eidx, int* __restrict__ count,
    const float* __restrict__ child_feats, const float* __restrict__ child_exists,
    const float* __restrict__ op_w, const float* __restrict__ op_b,
    u16* __restrict__ cf_a, unsigned* __restrict__ ipf0_m,
    const float* __restrict__ child_geo,
    const float* __restrict__ geo_w, const float* __restrict__ geo_b,
    const float* __restrict__ skip_w, const float* __restrict__ skip_b,
    unsigned* __restrict__ pg_m, unsigned* __restrict__ sg_m)
{
    __shared__ __align__(16) char sh[19456];
    const int b = blockIdx.x;
    if (b < 2) {
        conv_w_dev(edge_w, Wb, b);
    } else if (b < 1252) {
        int e = (b - 2) * 256 + threadIdx.x;
        atomicAdd(&count[eidx[2*e]], 1);
    } else if (b < 1409) {
        encode_dev(sh, b - 1252, child_feats, child_exists, op_w, op_b, cf_a, ipf0_m);
    } else {
        int g = b - 1409;
        int which = (g >= 157) ? 1 : 0;
        geo_dev(sh, which ? g - 157 : g, which,
                child_geo, child_exists, geo_w, geo_b, skip_w, skip_b, pg_m, sg_m);
    }
}

// ---------------------------------------------------------------------------
__global__ __launch_bounds__(1024) void scan_offsets(
    const int* __restrict__ count, int* __restrict__ offset)
{
    __shared__ int part[1024];
    const int t = threadIdx.x;
    const int lo = t * 20;
    const int hi = min(lo + 20, N_NODES);
    int s = 0;
    for (int n = lo; n < hi; ++n) s += count[n];
    part[t] = s;
    __syncthreads();
    for (int d = 1; d < 1024; d <<= 1) {
        int v = (t >= d) ? part[t - d] : 0;
        __syncthreads();
        part[t] += v;
        __syncthreads();
    }
    int run = (t > 0) ? part[t - 1] : 0;
    for (int n = lo; n < hi; ++n) { offset[n] = run; run += count[n]; }
}

// fill permuted edge arrays in CSR (from-sorted) order
__global__ __launch_bounds__(256) void fill_perm(
    const int* __restrict__ eidx, const float* __restrict__ ef,
    const int* __restrict__ offset, int* __restrict__ cursor,
    int* __restrict__ from_p, int* __restrict__ to_p, uint2* __restrict__ efb_p)
{
    int e = blockIdx.x * 256 + threadIdx.x;
    int2 p = ((const int2*)eidx)[e];
    int pos = offset[p.x] + atomicAdd(&cursor[p.x], 1);
    from_p[pos] = p.x; to_p[pos] = p.y;
    float4 e4 = ((const float4*)ef)[e];
    efb_p[pos] = make_uint2(
        (unsigned)f2bf(e4.x) | ((unsigned)f2bf(e4.y) << 16),
        (unsigned)f2bf(e4.z) | ((unsigned)f2bf(e4.w) << 16));
}

// ---------------------------------------------------------------------------
// Barrier-free MFMA edge pass: msg = leaky([cf[f]|cf[t]|ef] @ W.T + b)
// A fragments: direct 16B global loads from cf rows (L2-served gather;
// 4 quads of one lc cover a full 64B sector). B: whole 128x288 weight matrix
// preloaded to LDS once (1 barrier), ds_read_b128 fragments. No K-loop barriers.
// 256 edges x 128 ch per block; 8 waves in 4x2 grid (64x64 each); K = 9x32.
// STORE_MSG: LDS-transpose epilogue (reusing W region) -> coalesced stores.
// ---------------------------------------------------------------------------
template<int STORE_MSG>
__global__ __launch_bounds__(512, 4) void edge_mfma(
    const u16* __restrict__ cfb,       // [N,128] bf16 (gather source)
    const int* __restrict__ from_p,    // [E] sorted
    const int* __restrict__ to_p,      // [E] permuted
    const uint2* __restrict__ efb_p,   // [E] 4x bf16 packed
    const u16* __restrict__ Wb,        // [128,288] bf16 (padded)
    const float* __restrict__ bias,    // [128]
    u16* __restrict__ msgb,            // [E,128] bf16 (CSR order)
    int* __restrict__ ipf_out)         // [128]
{
    __shared__ __align__(16) u16 smem[128 * WSTR];   // 75776 B (W; reused for transpose)
    __shared__ int colmax_s[128];

    const int t    = threadIdx.x;
    const int base = blockIdx.x * 256;          // 1250 blocks exact
    const int wave = t >> 6, l = t & 63;
    const int quad = l >> 4, lc = l & 15;
    const int R0 = (wave >> 1) * 64;
    const int C0 = (wave & 1) * 64;

    // preload W into LDS (each thread: row t>>2, quarter t&3 = 9 uint4)
    {
        const int r = t >> 2, q = t & 3;
        const uint4* src = (const uint4*)(Wb + r * KPAD + q * 72);
        uint4* dst = (uint4*)(smem + r * WSTR + q * 72);
        #pragma unroll
        for (int i = 0; i < 9; ++i) dst[i] = src[i];
    }
    if (t < 128) colmax_s[t] = 0;

    // per-lane edge metadata for the wave's 4 row-groups
    int nf[4], nt[4]; uint2 efr[4];
    #pragma unroll
    for (int ti = 0; ti < 4; ++ti) {
        int e = base + R0 + ti * 16 + lc;
        nf[ti]  = from_p[e];
        nt[ti]  = to_p[e];
        efr[ti] = efb_p[e];
    }
    __syncthreads();   // W resident

    f32x4 acc[4][4];
    #pragma unroll
    for (int i = 0; i < 4; ++i)
        #pragma unroll
        for (int j = 0; j < 4; ++j) acc[i][j] = (f32x4){0.f, 0.f, 0.f, 0.f};

    // K loop: 8 gather chunks + 1 edge-type chunk; NO barriers
    #pragma unroll
    for (int c = 0; c < 8; ++c) {
        bf16x8 af[4], bfr[4];
        #pragma unroll
        for (int ti = 0; ti < 4; ++ti) {
            int node = (c < 4) ? nf[ti] : nt[ti];
            af[ti] = *(const bf16x8*)(cfb + node * HD + (c & 3) * 32 + quad * 8);
        }
        #pragma unroll
        for (int tj = 0; tj < 4; ++tj)
            bfr[tj] = *(const bf16x8*)(smem + (C0 + tj * 16 + lc) * WSTR + c * 32 + quad * 8);
        #pragma unroll
        for (int ti = 0; ti < 4; ++ti)
            #pragma unroll
            for (int tj = 0; tj < 4; ++tj)
                acc[ti][tj] = __builtin_amdgcn_mfma_f32_16x16x32_bf16(
                    af[ti], bfr[tj], acc[ti][tj], 0, 0, 0);
    }
    {   // chunk 8: edge-type features (k 256..259 real, rest zero)
        bf16x8 af[4], bfr[4];
        #pragma unroll
        for (int ti = 0; ti < 4; ++ti) {
            union { bf16x8 v; unsigned u[4]; } p;
            p.u[0] = efr[ti].x; p.u[1] = efr[ti].y; p.u[2] = 0u; p.u[3] = 0u;
            union { bf16x8 v; unsigned u[4]; } z;
            z.u[0] = z.u[1] = z.u[2] = z.u[3] = 0u;
            af[ti] = (quad == 0) ? p.v : z.v;
        }
        #pragma unroll
        for (int tj = 0; tj < 4; ++tj)
            bfr[tj] = *(const bf16x8*)(smem + (C0 + tj * 16 + lc) * WSTR + 8 * 32 + quad * 8);
        #pragma unroll
        for (int ti = 0; ti < 4; ++ti)
            #pragma unroll
            for (int tj = 0; tj < 4; ++tj)
                acc[ti][tj] = __builtin_amdgcn_mfma_f32_16x16x32_bf16(
                    af[ti], bfr[tj], acc[ti][tj], 0, 0, 0);
    }

    // bias + leaky in-place; per-channel block max
    #pragma unroll
    for (int tj = 0; tj < 4; ++tj) {
        const int col = C0 + tj * 16 + lc;
        const float bc = bias[col];
        float mx = 0.f;
        #pragma unroll
        for (int ti = 0; ti < 4; ++ti) {
            #pragma unroll
            for (int r = 0; r < 4; ++r) {
                float x = leaky(acc[ti][tj][r] + bc);
                acc[ti][tj][r] = x;
                mx = fmaxf(mx, x);
            }
        }
        atomicMax(&colmax_s[col], __float_as_int(mx));   // mx >= 0: int-bits OK
    }
    __syncthreads();   // colmax done; all W reads drained (smem reusable)
    if (t < 128) atomicMax(&ipf_out[t], colmax_s[t]);

    if (STORE_MSG) {
        // two-phase LDS transpose (128 rows x 128 ch, stride TSTR) -> coalesced uint4
        const int h = wave >> 2;        // waves 0-3 own rows 0..127; 4-7 own 128..255
        #pragma unroll
        for (int ph = 0; ph < 2; ++ph) {
            if (h == ph) {
                const int rb = R0 & 64;
                #pragma unroll
                for (int ti = 0; ti < 4; ++ti)
                    #pragma unroll
                    for (int tj = 0; tj < 4; ++tj) {
                        const int col = C0 + tj * 16 + lc;
                        #pragma unroll
                        for (int r = 0; r < 4; ++r)
                            smem[(rb + ti * 16 + quad * 4 + r) * TSTR + col]
                                = f2bf(acc[ti][tj][r]);
                    }
            }
            __syncthreads();
            #pragma unroll
            for (int i = 0; i < 4; ++i) {
                int idx = t + i * 512;          // 2048 = 128 rows x 16 uint4
                int row = idx >> 4, c16 = idx & 15;
                uint4 v = *(const uint4*)(smem + row * TSTR + c16 * 8);
                *(uint4*)(msgb + (size_t)(base + ph * 128 + row) * HD + c16 * 8) = v;
            }
            __syncthreads();
        }
    }
}

// ---------------------------------------------------------------------------
// segment max over CSR-contiguous message rows; 4 nodes per 512-thread block
// ---------------------------------------------------------------------------
__global__ __launch_bounds__(512) void segmax(
    const u16* __restrict__ msgb,   // [E,128] bf16, CSR order
    const int* __restrict__ offset, const int* __restrict__ count,
    u16* __restrict__ cf_b)         // [N,128] bf16
{
    const int n = blockIdx.x * 4 + (threadIdx.x >> 7);
    const int t = threadIdx.x & 127;
    const int off = offset[n];
    const int deg = count[n];
    float m = 0.f;
    const u16* p = msgb + (size_t)off * HD + t;
    int d = 0;
    for (; d + 1 < deg; d += 2) {
        float a = bf2f(p[(size_t)d * HD]);
        float b = bf2f(p[(size_t)(d + 1) * HD]);
        m = fmaxf(m, fmaxf(a, b));
    }
    if (d < deg) m = fmaxf(m, bf2f(p[(size_t)d * HD]));
    cf_b[(size_t)n * HD + t] = f2bf(m);
}

// ---------------------------------------------------------------------------
// fused heads: block 0 = parent_feat, block 1 = parent_geo
// ---------------------------------------------------------------------------
__global__ __launch_bounds__(128) void heads(
    const unsigned* __restrict__ ipf0_m,
    const float* __restrict__ ipf1, const float* __restrict__ ipf2,
    const float* __restrict__ secW, const float* __restrict__ secB,
    const unsigned* __restrict__ pg_m, const unsigned* __restrict__ sg_m,
    const float* __restrict__ geoW, const float* __restrict__ geoB,
    const float* __restrict__ gnw, const float* __restrict__ gnb,
    float* __restrict__ out)
{
    const int t = threadIdx.x;
    if (blockIdx.x == 0) {
        __shared__ float s[384];
        s[t]       = funmap(ipf0_m[t]);
        s[128 + t] = ipf1[t];
        s[256 + t] = ipf2[t];
        __syncthreads();
        float acc = secB[t];
        #pragma unroll 4
        for (int k = 0; k < 384; ++k) acc = fmaf(s[k], secW[t*384 + k], acc);
        out[t] = leaky(acc);
    } else {
        __shared__ float pg[128];
        __shared__ float tt[128];
        pg[t] = leaky(funmap(pg_m[t]));
        float sg = leaky(funmap(sg_m[t]));
        __syncthreads();
        float acc = geoB[t];
        #pragma unroll 4
        for (int k = 0; k < 128; ++k) acc = fmaf(pg[k], geoW[t*128 + k], acc);
        tt[t] = acc;
        __syncthreads();
        const int g = (t >> 3) << 3;
        float mu = 0.f, m2 = 0.f;
        #pragma unroll
        for (int q = 0; q < 8; ++q) { float x = tt[g + q]; mu += x; m2 += x*x; }
        mu *= 0.125f;
        m2 = m2 * 0.125f - mu * mu;
        float xn = (acc - mu) * rsqrtf(m2 + 1e-5f);
        out[128 + t] = leaky(sg + xn * gnw[t] + gnb[t]);
    }
}

// ---------------------------------------------------------------------------
extern "C" void kernel_launch(void* const* d_in, const int* in_sizes, int n_in,
                              void* d_out, int out_size, void* d_ws, size_t ws_size,
                              hipStream_t stream)
{
    const float* child_feats  = (const float*)d_in[0];
    const float* child_geo    = (const float*)d_in[1];
    const float* child_exists = (const float*)d_in[2];
    const float* etoh         = (const float*)d_in[3];
    const int*   eidx         = (const int*)  d_in[4];
    const float* op_w   = (const float*)d_in[5];
    const float* op_b   = (const float*)d_in[6];
    const float* sec_w  = (const float*)d_in[7];
    const float* sec_b  = (const float*)d_in[8];
    const float* edge_w = (const float*)d_in[9];
    const float* edge_b = (const float*)d_in[10];
    const float* geo_w  = (const float*)d_in[11];
    const float* geo_b  = (const float*)d_in[12];
    const float* sgeo_w = (const float*)d_in[13];
    const float* sgeo_b = (const float*)d_in[14];
    const float* gn_w   = (const float*)d_in[15];
    const float* gn_b   = (const float*)d_in[16];
    const float* skip_w = (const float*)d_in[17];
    const float* skip_b = (const float*)d_in[18];
    float* out = (float*)d_out;

    // workspace layout (all offsets 16B aligned)
    char* ws = (char*)d_ws;
    size_t off = 0;
    u16*   cf_a   = (u16*)(ws + off);   off += (size_t)N_NODES*HD*2;    // 5.12 MB
    u16*   cf_bb  = (u16*)(ws + off);   off += (size_t)N_NODES*HD*2;    // 5.12 MB
    u16*   msgb   = (u16*)(ws + off);   off += (size_t)N_EDGES*HD*2;    // 81.92 MB
    u16*   Wb     = (u16*)(ws + off);   off += (size_t)2*128*KPAD*2;    // 147 KB
    int*   from_p = (int*)(ws + off);   off += (size_t)N_EDGES*4;       // 1.28 MB
    int*   to_p   = (int*)(ws + off);   off += (size_t)N_EDGES*4;       // 1.28 MB
    uint2* efb_p  = (uint2*)(ws + off); off += (size_t)N_EDGES*8;       // 2.56 MB
    int*   offs   = (int*)(ws + off);   off += (size_t)N_NODES*4;       // 80 KB
    char*  zero0  = ws + off;
    unsigned* ipf0_m = (unsigned*)(ws + off); off += 128*4;
    float*    ipf1   = (float*)(ws + off);    off += 128*4;
    float*    ipf2   = (float*)(ws + off);    off += 128*4;
    unsigned* pg_m   = (unsigned*)(ws + off); off += 128*4;
    unsigned* sg_m   = (unsigned*)(ws + off); off += 128*4;
    int*      count  = (int*)(ws + off);      off += (size_t)N_NODES*4;
    int*      cursor = (int*)(ws + off);      off += (size_t)N_NODES*4;
    size_t zero_bytes = (size_t)(ws + off - zero0);

    hipMemsetAsync(zero0, 0, zero_bytes, stream);

    // conv_w + histogram + encode + geo in one launch
    fused_front<<<1723, 256, 0, stream>>>(
        edge_w, Wb, eidx, count,
        child_feats, child_exists, op_w, op_b, cf_a, ipf0_m,
        child_geo, geo_w, geo_b, skip_w, skip_b, pg_m, sg_m);

    scan_offsets<<<1, 1024, 0, stream>>>(count, offs);

    fill_perm<<<N_EDGES/256, 256, 0, stream>>>(
        eidx, etoh, offs, cursor, from_p, to_p, efb_p);

    // iter 1: barrier-free MFMA messages -> msgb (CSR order) + column max
    edge_mfma<1><<<N_EDGES/256, 512, 0, stream>>>(
        cf_a, from_p, to_p, efb_p, Wb, edge_b, msgb, (int*)ipf1);

    // contiguous segment max -> cf_bb (bf16)
    segmax<<<N_NODES/4, 512, 0, stream>>>(msgb, offs, count, cf_bb);

    // iter 2: only column max needed
    edge_mfma<0><<<N_EDGES/256, 512, 0, stream>>>(
        cf_bb, from_p, to_p, efb_p, Wb + 128*KPAD, edge_b + 128, nullptr, (int*)ipf2);

    heads<<<2, 128, 0, stream>>>(ipf0_m, ipf1, ipf2, sec_w, sec_b,
                                 pg_m, sg_m, sgeo_w, sgeo_b, gn_w, gn_b, out);
}

// Round 8
// 351.463 us; speedup vs baseline: 1.1710x; 1.0047x over previous
//
#include <hip/hip_runtime.h>

#define N_NODES 20000
#define N_EDGES 320000
#define HD 128
#define FIN 162      // 24 + 10 + 128
#define KE 260       // 2*H + ETN
#define KPAD 288     // edge K padded: 9 chunks of 32
#define KOP 192      // encode K padded: 6 chunks of 32
#define WSTR 296     // edge W LDS row stride (u16)
#define OSTR 200     // encode W LDS row stride (u16)
#define GSTR 136     // geo W LDS row stride (u16)
#define TSTR 136     // transpose row stride (u16)

typedef unsigned short u16;
typedef __attribute__((ext_vector_type(8))) short bf16x8;
typedef __attribute__((ext_vector_type(4))) float f32x4;

__device__ __forceinline__ float leaky(float x){ return x > 0.f ? x : 0.01f*x; }
__device__ __forceinline__ unsigned fmap(float f){
    unsigned u = __float_as_uint(f);
    return (u & 0x80000000u) ? ~u : (u | 0x80000000u);
}
__device__ __forceinline__ float funmap(unsigned u){
    return __uint_as_float((u & 0x80000000u) ? (u & 0x7fffffffu) : ~u);
}
__device__ __forceinline__ unsigned umax_(unsigned a, unsigned b){ return a > b ? a : b; }
__device__ __forceinline__ u16 f2bf(float x){
    unsigned b = __float_as_uint(x);
    return (u16)((b + 0x7fffu + ((b >> 16) & 1u)) >> 16);
}
__device__ __forceinline__ float bf2f(u16 u){
    return __uint_as_float(((unsigned)u) << 16);
}

// ---------------------------------------------------------------------------
// prep: weight bf16 conversion + input bf16 conversion + from-histogram
// blocks: [0,2) edge W | 2 op_w | 3 geo_w | 4 skip_w | [5,162) feats |
//         [162,319) geo feats | [319,1569) histogram
// ---------------------------------------------------------------------------
__global__ __launch_bounds__(256) void prep(
    const float* __restrict__ edge_w, u16* __restrict__ Wb,
    const float* __restrict__ op_w,   u16* __restrict__ Wop,
    const float* __restrict__ geo_w,  u16* __restrict__ Wgeo,
    const float* __restrict__ skip_w, u16* __restrict__ Wskip,
    const float* __restrict__ feats,  u16* __restrict__ featsb,
    const float* __restrict__ geof,   u16* __restrict__ geob,
    const int* __restrict__ eidx, int* __restrict__ count)
{
    const int b = blockIdx.x, t = threadIdx.x;
    if (b < 2) {
        const float* src = edge_w + (size_t)b * 128 * KE;
        u16* dst = Wb + (size_t)b * 128 * KPAD;
        for (int i = t; i < 128 * KPAD; i += 256) {
            int h = i / KPAD, k = i - h * KPAD;
            dst[i] = (k < KE) ? f2bf(src[h * KE + k]) : (u16)0;
        }
    } else if (b == 2) {
        for (int i = t; i < 128 * KOP; i += 256) {
            int h = i / KOP, k = i - h * KOP;
            Wop[i] = (k < FIN) ? f2bf(op_w[h * FIN + k]) : (u16)0;
        }
    } else if (b == 3) {
        for (int i = t; i < 128 * 128; i += 256) Wgeo[i] = f2bf(geo_w[i]);
    } else if (b == 4) {
        for (int i = t; i < 128 * 128; i += 256) Wskip[i] = f2bf(skip_w[i]);
    } else if (b < 162) {
        const int rbase = (b - 5) * 128;
        for (int i = t; i < 128 * KOP; i += 256) {
            int r = i / KOP, k = i - r * KOP;
            int n = rbase + r;
            if (n < N_NODES)
                featsb[(size_t)n * KOP + k] = (k < FIN) ? f2bf(feats[(size_t)n * FIN + k]) : (u16)0;
        }
    } else if (b < 319) {
        const int obase = (b - 162) * 2048;   // uint4 outputs (8 bf16 each)
        for (int j = t; j < 2048; j += 256) {
            int o = obase + j;
            if (o < N_NODES * HD / 8) {
                const float4* s = (const float4*)geof + (size_t)o * 2;
                float4 a = s[0], bb = s[1];
                union { u16 us[8]; uint4 v; } pk;
                pk.us[0]=f2bf(a.x); pk.us[1]=f2bf(a.y); pk.us[2]=f2bf(a.z); pk.us[3]=f2bf(a.w);
                pk.us[4]=f2bf(bb.x); pk.us[5]=f2bf(bb.y); pk.us[6]=f2bf(bb.z); pk.us[7]=f2bf(bb.w);
                ((uint4*)geob)[o] = pk.v;
            }
        }
    } else {
        int e = (b - 319) * 256 + t;
        atomicAdd(&count[eidx[2*e]], 1);
    }
}

// ---------------------------------------------------------------------------
__global__ __launch_bounds__(1024) void scan_offsets(
    const int* __restrict__ count, int* __restrict__ offset)
{
    __shared__ int part[1024];
    const int t = threadIdx.x;
    const int lo = t * 20;
    const int hi = min(lo + 20, N_NODES);
    int s = 0;
    for (int n = lo; n < hi; ++n) s += count[n];
    part[t] = s;
    __syncthreads();
    for (int d = 1; d < 1024; d <<= 1) {
        int v = (t >= d) ? part[t - d] : 0;
        __syncthreads();
        part[t] += v;
        __syncthreads();
    }
    int run = (t > 0) ? part[t - 1] : 0;
    for (int n = lo; n < hi; ++n) { offset[n] = run; run += count[n]; }
}

__global__ __launch_bounds__(256) void fill_perm(
    const int* __restrict__ eidx, const float* __restrict__ ef,
    const int* __restrict__ offset, int* __restrict__ cursor,
    int* __restrict__ from_p, int* __restrict__ to_p, uint2* __restrict__ efb_p)
{
    int e = blockIdx.x * 256 + threadIdx.x;
    int2 p = ((const int2*)eidx)[e];
    int pos = offset[p.x] + atomicAdd(&cursor[p.x], 1);
    from_p[pos] = p.x; to_p[pos] = p.y;
    float4 e4 = ((const float4*)ef)[e];
    efb_p[pos] = make_uint2(
        (unsigned)f2bf(e4.x) | ((unsigned)f2bf(e4.y) << 16),
        (unsigned)f2bf(e4.z) | ((unsigned)f2bf(e4.w) << 16));
}

// ---------------------------------------------------------------------------
// node MFMA: blocks [0,157) encode | [157,314) geo/pg | [314,471) skip/sg
// 256 thr = 4 waves 2x2 (64 rows x 64 cols each), 128-node x 128-ch tile
// barrier-free K-loop: A direct bf16 global loads, W in LDS
// ---------------------------------------------------------------------------
__global__ __launch_bounds__(256) void node_mfma(
    const u16* __restrict__ featsb,   // [N,192] bf16
    const u16* __restrict__ geob,     // [N,128] bf16
    const float* __restrict__ exists,
    const u16* __restrict__ Wop, const float* __restrict__ op_b,
    const u16* __restrict__ Wgeo, const float* __restrict__ geo_b,
    const u16* __restrict__ Wskip, const float* __restrict__ skip_b,
    u16* __restrict__ cf_a,           // [N,128] bf16 out (encode only)
    unsigned* __restrict__ ipf0_m, unsigned* __restrict__ pg_m,
    unsigned* __restrict__ sg_m)
{
    __shared__ __align__(16) u16 smem[128 * OSTR];   // 51200 B (W; reused for transpose)
    __shared__ float ex_s[128];
    __shared__ unsigned colmax_s[128];

    const int b = blockIdx.x, t = threadIdx.x;
    const int mode = (b < 157) ? 0 : (b < 314) ? 1 : 2;
    const int bx = b - (mode == 0 ? 0 : mode == 1 ? 157 : 314);
    const int base = bx * 128;
    const int wave = t >> 6, l = t & 63;
    const int quad = l >> 4, lc = l & 15;
    const int R0 = (wave >> 1) * 64;
    const int C0 = (wave & 1) * 64;

    const u16* W = (mode == 0) ? Wop : (mode == 1) ? Wgeo : Wskip;
    const float* bias = (mode == 0) ? op_b : (mode == 1) ? geo_b : skip_b;
    unsigned* accout = (mode == 0) ? ipf0_m : (mode == 1) ? pg_m : sg_m;
    const int KW = (mode == 0) ? KOP : HD;
    const int SW = (mode == 0) ? OSTR : GSTR;
    const int NCH = (mode == 0) ? 6 : 4;
    const u16* A = (mode == 0) ? featsb : geob;

    // preload W to LDS: each thread row t>>1, half t&1
    {
        const int r = t >> 1, half = t & 1;
        const int nu4 = KW / 16;                  // uint4 per half-row
        const uint4* src = (const uint4*)(W + (size_t)r * KW) + half * nu4;
        uint4* dst = (uint4*)(smem + r * SW) + half * nu4;
        for (int i = 0; i < nu4; ++i) dst[i] = src[i];
    }
    if (t < 128) {
        int n = base + t; if (n >= N_NODES) n = N_NODES - 1;
        ex_s[t] = exists[n];
        colmax_s[t] = 0u;
    }
    __syncthreads();

    f32x4 acc[4][4];
    #pragma unroll
    for (int i = 0; i < 4; ++i)
        #pragma unroll
        for (int j = 0; j < 4; ++j) acc[i][j] = (f32x4){0.f, 0.f, 0.f, 0.f};

    // node ids for this wave's rows
    int nd[4];
    #pragma unroll
    for (int ti = 0; ti < 4; ++ti) {
        int n = base + R0 + ti * 16 + lc;
        nd[ti] = (n < N_NODES) ? n : N_NODES - 1;
    }

    for (int c = 0; c < NCH; ++c) {
        bf16x8 af[4], bfr[4];
        #pragma unroll
        for (int ti = 0; ti < 4; ++ti)
            af[ti] = *(const bf16x8*)(A + (size_t)nd[ti] * KW + c * 32 + quad * 8);
        #pragma unroll
        for (int tj = 0; tj < 4; ++tj)
            bfr[tj] = *(const bf16x8*)(smem + (C0 + tj * 16 + lc) * SW + c * 32 + quad * 8);
        #pragma unroll
        for (int ti = 0; ti < 4; ++ti)
            #pragma unroll
            for (int tj = 0; tj < 4; ++tj)
                acc[ti][tj] = __builtin_amdgcn_mfma_f32_16x16x32_bf16(
                    af[ti], bfr[tj], acc[ti][tj], 0, 0, 0);
    }

    // epilogue: x = (acc + bias)*ex ; colmax (mapped) ; encode stores cf_a
    #pragma unroll
    for (int tj = 0; tj < 4; ++tj) {
        const int col = C0 + tj * 16 + lc;
        const float bc = bias[col];
        unsigned mx = 0u;
        #pragma unroll
        for (int ti = 0; ti < 4; ++ti) {
            #pragma unroll
            for (int r = 0; r < 4; ++r) {
                int row = R0 + ti * 16 + quad * 4 + r;
                float x = (acc[ti][tj][r] + bc) * ex_s[row];
                acc[ti][tj][r] = x;
                mx = umax_(mx, fmap(x));
            }
        }
        atomicMax(&colmax_s[col], mx);
    }
    __syncthreads();   // colmax done + all W reads drained
    if (t < 128) atomicMax(&accout[t], colmax_s[t]);

    if (mode == 0) {
        // transpose 128x128 through LDS (stride TSTR) -> coalesced uint4 stores
        #pragma unroll
        for (int ti = 0; ti < 4; ++ti)
            #pragma unroll
            for (int tj = 0; tj < 4; ++tj) {
                const int col = C0 + tj * 16 + lc;
                #pragma unroll
                for (int r = 0; r < 4; ++r)
                    smem[(R0 + ti * 16 + quad * 4 + r) * TSTR + col] = f2bf(acc[ti][tj][r]);
            }
        __syncthreads();
        #pragma unroll
        for (int i = 0; i < 8; ++i) {
            int idx = t + i * 256;              // 2048 = 128 rows x 16 uint4
            int row = idx >> 4, c16 = idx & 15;
            int n = base + row;
            if (n < N_NODES) {
                uint4 v = *(const uint4*)(smem + row * TSTR + c16 * 8);
                *(uint4*)(cf_a + (size_t)n * HD + c16 * 8) = v;
            }
        }
    }
}

// ---------------------------------------------------------------------------
// Barrier-free MFMA edge pass: msg = leaky([cf[f]|cf[t]|ef] @ W.T + b)
// 256 edges x 128 ch per block; 8 waves 4x2; K = 9x32; W in LDS (1 barrier).
// REDUCE: single-phase 256-row LDS transpose, then in-LDS per-from-node
//   segment max. Interior nodes -> bf16 stores; boundary -> fp32 atomicMax.
// ---------------------------------------------------------------------------
template<int REDUCE>
__global__ __launch_bounds__(512, 4) void edge_mfma(
    const u16* __restrict__ cfb,       // [N,128] bf16 (gather source)
    const int* __restrict__ from_p,    // [E] sorted
    const int* __restrict__ to_p,      // [E] permuted
    const uint2* __restrict__ efb_p,   // [E] 4x bf16 packed
    const u16* __restrict__ Wb,        // [128,288] bf16 (padded)
    const float* __restrict__ bias,    // [128]
    const int* __restrict__ offs,      // [N] CSR offsets
    const int* __restrict__ cnt,       // [N] degrees
    u16* __restrict__ cf_bb,           // [N,128] bf16 out (interior nodes)
    float* __restrict__ cf_b32,        // [N,128] fp32 atomic buffer (init 0)
    int* __restrict__ ipf_out)         // [128]
{
    __shared__ __align__(16) u16 smem[128 * WSTR];   // 75776 B (W; reused: 256xTSTR transpose)
    __shared__ int colmax_s[128];

    const int t    = threadIdx.x;
    const int base = blockIdx.x * 256;          // 1250 blocks exact
    const int wave = t >> 6, l = t & 63;
    const int quad = l >> 4, lc = l & 15;
    const int R0 = (wave >> 1) * 64;
    const int C0 = (wave & 1) * 64;

    // preload W into LDS
    {
        const int r = t >> 2, q = t & 3;
        const uint4* src = (const uint4*)(Wb + r * KPAD + q * 72);
        uint4* dst = (uint4*)(smem + r * WSTR + q * 72);
        #pragma unroll
        for (int i = 0; i < 9; ++i) dst[i] = src[i];
    }
    if (t < 128) colmax_s[t] = 0;

    int nf[4], nt[4]; uint2 efr[4];
    #pragma unroll
    for (int ti = 0; ti < 4; ++ti) {
        int e = base + R0 + ti * 16 + lc;
        nf[ti]  = from_p[e];
        nt[ti]  = to_p[e];
        efr[ti] = efb_p[e];
    }
    __syncthreads();   // W resident

    f32x4 acc[4][4];
    #pragma unroll
    for (int i = 0; i < 4; ++i)
        #pragma unroll
        for (int j = 0; j < 4; ++j) acc[i][j] = (f32x4){0.f, 0.f, 0.f, 0.f};

    #pragma unroll
    for (int c = 0; c < 8; ++c) {
        bf16x8 af[4], bfr[4];
        #pragma unroll
        for (int ti = 0; ti < 4; ++ti) {
            int node = (c < 4) ? nf[ti] : nt[ti];
            af[ti] = *(const bf16x8*)(cfb + node * HD + (c & 3) * 32 + quad * 8);
        }
        #pragma unroll
        for (int tj = 0; tj < 4; ++tj)
            bfr[tj] = *(const bf16x8*)(smem + (C0 + tj * 16 + lc) * WSTR + c * 32 + quad * 8);
        #pragma unroll
        for (int ti = 0; ti < 4; ++ti)
            #pragma unroll
            for (int tj = 0; tj < 4; ++tj)
                acc[ti][tj] = __builtin_amdgcn_mfma_f32_16x16x32_bf16(
                    af[ti], bfr[tj], acc[ti][tj], 0, 0, 0);
    }
    {   // chunk 8: edge-type features (k 256..259 real, rest zero)
        bf16x8 af[4], bfr[4];
        #pragma unroll
        for (int ti = 0; ti < 4; ++ti) {
            union { bf16x8 v; unsigned u[4]; } p;
            p.u[0] = efr[ti].x; p.u[1] = efr[ti].y; p.u[2] = 0u; p.u[3] = 0u;
            union { bf16x8 v; unsigned u[4]; } z;
            z.u[0] = z.u[1] = z.u[2] = z.u[3] = 0u;
            af[ti] = (quad == 0) ? p.v : z.v;
        }
        #pragma unroll
        for (int tj = 0; tj < 4; ++tj)
            bfr[tj] = *(const bf16x8*)(smem + (C0 + tj * 16 + lc) * WSTR + 8 * 32 + quad * 8);
        #pragma unroll
        for (int ti = 0; ti < 4; ++ti)
            #pragma unroll
            for (int tj = 0; tj < 4; ++tj)
                acc[ti][tj] = __builtin_amdgcn_mfma_f32_16x16x32_bf16(
                    af[ti], bfr[tj], acc[ti][tj], 0, 0, 0);
    }

    // bias + leaky; per-channel block max
    #pragma unroll
    for (int tj = 0; tj < 4; ++tj) {
        const int col = C0 + tj * 16 + lc;
        const float bc = bias[col];
        float mx = 0.f;
        #pragma unroll
        for (int ti = 0; ti < 4; ++ti) {
            #pragma unroll
            for (int r = 0; r < 4; ++r) {
                float x = leaky(acc[ti][tj][r] + bc);
                acc[ti][tj][r] = x;
                mx = fmaxf(mx, x);
            }
        }
        atomicMax(&colmax_s[col], __float_as_int(mx));   // mx >= 0: int-bits OK
    }
    __syncthreads();   // colmax done; all W reads drained (smem reusable)
    if (t < 128) atomicMax(&ipf_out[t], colmax_s[t]);

    if (REDUCE) {
        // single-phase transpose of all 256 rows (256*TSTR = 34816 u16 fits)
        #pragma unroll
        for (int ti = 0; ti < 4; ++ti)
            #pragma unroll
            for (int tj = 0; tj < 4; ++tj) {
                const int col = C0 + tj * 16 + lc;
                #pragma unroll
                for (int r = 0; r < 4; ++r)
                    smem[(R0 + ti * 16 + quad * 4 + r) * TSTR + col] = f2bf(acc[ti][tj][r]);
            }
        __syncthreads();
        // in-LDS per-from-node segment max (rows are CSR-contiguous)
        const int nfirst = from_p[base];
        const int nlast  = from_p[base + 255];
        const int ch = t & 127;
        for (int n = nfirst + (t >> 7); n <= nlast; n += 4) {
            int o = offs[n], c = cnt[n];
            int lo = o - base, hi = o + c - base;
            int lo2 = lo > 0 ? lo : 0;
            int hi2 = hi < 256 ? hi : 256;
            if (lo2 >= hi2) continue;
            float m = 0.f;       // 0 floor matches zeros.at[].max
            for (int r = lo2; r < hi2; ++r)
                m = fmaxf(m, bf2f(smem[r * TSTR + ch]));
            if (lo >= 0 && hi <= 256)
                cf_bb[(size_t)n * HD + ch] = f2bf(m);
            else
                atomicMax((int*)&cf_b32[(size_t)n * HD + ch], __float_as_int(m));
        }
    }
}

// ---------------------------------------------------------------------------
// fixup: boundary nodes -> cf_bb from the fp32 atomic buffer
// ---------------------------------------------------------------------------
__global__ __launch_bounds__(256) void fixup(
    const int* __restrict__ offs, const int* __restrict__ cnt,
    const float* __restrict__ cf_b32, u16* __restrict__ cf_bb)
{
    const int n = blockIdx.x * 2 + (threadIdx.x >> 7);
    const int ch = threadIdx.x & 127;
    int o = offs[n], c = cnt[n];
    if (c > 0 && (o >> 8) != ((o + c - 1) >> 8))
        cf_bb[(size_t)n * HD + ch] = f2bf(cf_b32[(size_t)n * HD + ch]);
}

// ---------------------------------------------------------------------------
// fused heads: block 0 = parent_feat, block 1 = parent_geo
// ---------------------------------------------------------------------------
__global__ __launch_bounds__(128) void heads(
    const unsigned* __restrict__ ipf0_m,
    const float* __restrict__ ipf1, const float* __restrict__ ipf2,
    const float* __restrict__ secW, const float* __restrict__ secB,
    const unsigned* __restrict__ pg_m, const unsigned* __restrict__ sg_m,
    const float* __restrict__ geoW, const float* __restrict__ geoB,
    const float* __restrict__ gnw, const float* __restrict__ gnb,
    float* __restrict__ out)
{
    const int t = threadIdx.x;
    if (blockIdx.x == 0) {
        __shared__ float s[384];
        s[t]       = funmap(ipf0_m[t]);
        s[128 + t] = ipf1[t];
        s[256 + t] = ipf2[t];
        __syncthreads();
        float acc = secB[t];
        #pragma unroll 4
        for (int k = 0; k < 384; ++k) acc = fmaf(s[k], secW[t*384 + k], acc);
        out[t] = leaky(acc);
    } else {
        __shared__ float pg[128];
        __shared__ float tt[128];
        pg[t] = leaky(funmap(pg_m[t]));
        float sg = leaky(funmap(sg_m[t]));
        __syncthreads();
        float acc = geoB[t];
        #pragma unroll 4
        for (int k = 0; k < 128; ++k) acc = fmaf(pg[k], geoW[t*128 + k], acc);
        tt[t] = acc;
        __syncthreads();
        const int g = (t >> 3) << 3;
        float mu = 0.f, m2 = 0.f;
        #pragma unroll
        for (int q = 0; q < 8; ++q) { float x = tt[g + q]; mu += x; m2 += x*x; }
        mu *= 0.125f;
        m2 = m2 * 0.125f - mu * mu;
        float xn = (acc - mu) * rsqrtf(m2 + 1e-5f);
        out[128 + t] = leaky(sg + xn * gnw[t] + gnb[t]);
    }
}

// ---------------------------------------------------------------------------
extern "C" void kernel_launch(void* const* d_in, const int* in_sizes, int n_in,
                              void* d_out, int out_size, void* d_ws, size_t ws_size,
                              hipStream_t stream)
{
    const float* child_feats  = (const float*)d_in[0];
    const float* child_geo    = (const float*)d_in[1];
    const float* child_exists = (const float*)d_in[2];
    const float* etoh         = (const float*)d_in[3];
    const int*   eidx         = (const int*)  d_in[4];
    const float* op_w   = (const float*)d_in[5];
    const float* op_b   = (const float*)d_in[6];
    const float* sec_w  = (const float*)d_in[7];
    const float* sec_b  = (const float*)d_in[8];
    const float* edge_w = (const float*)d_in[9];
    const float* edge_b = (const float*)d_in[10];
    const float* geo_w  = (const float*)d_in[11];
    const float* geo_b  = (const float*)d_in[12];
    const float* sgeo_w = (const float*)d_in[13];
    const float* sgeo_b = (const float*)d_in[14];
    const float* gn_w   = (const float*)d_in[15];
    const float* gn_b   = (const float*)d_in[16];
    const float* skip_w = (const float*)d_in[17];
    const float* skip_b = (const float*)d_in[18];
    float* out = (float*)d_out;

    // workspace layout (all offsets 16B aligned)
    char* ws = (char*)d_ws;
    size_t off = 0;
    u16*   cf_a   = (u16*)(ws + off);   off += (size_t)N_NODES*HD*2;     // 5.12 MB
    u16*   featsb = (u16*)(ws + off);   off += (size_t)N_NODES*KOP*2;    // 7.68 MB
    u16*   geob   = (u16*)(ws + off);   off += (size_t)N_NODES*HD*2;     // 5.12 MB
    u16*   Wb     = (u16*)(ws + off);   off += (size_t)2*128*KPAD*2;     // 147 KB
    u16*   Wop    = (u16*)(ws + off);   off += (size_t)128*KOP*2;        // 49 KB
    u16*   Wgeo   = (u16*)(ws + off);   off += (size_t)128*128*2;        // 32 KB
    u16*   Wskip  = (u16*)(ws + off);   off += (size_t)128*128*2;        // 32 KB
    int*   from_p = (int*)(ws + off);   off += (size_t)N_EDGES*4;        // 1.28 MB
    int*   to_p   = (int*)(ws + off);   off += (size_t)N_EDGES*4;        // 1.28 MB
    uint2* efb_p  = (uint2*)(ws + off); off += (size_t)N_EDGES*8;        // 2.56 MB
    int*   offs   = (int*)(ws + off);   off += (size_t)N_NODES*4;        // 80 KB
    char*  zero0  = ws + off;
    u16*   cf_bb  = (u16*)(ws + off);         off += (size_t)N_NODES*HD*2;  // 5.12 MB
    float* cf_b32 = (float*)(ws + off);       off += (size_t)N_NODES*HD*4;  // 10.24 MB
    unsigned* ipf0_m = (unsigned*)(ws + off); off += 128*4;
    float*    ipf1   = (float*)(ws + off);    off += 128*4;
    float*    ipf2   = (float*)(ws + off);    off += 128*4;
    unsigned* pg_m   = (unsigned*)(ws + off); off += 128*4;
    unsigned* sg_m   = (unsigned*)(ws + off); off += 128*4;
    int*      count  = (int*)(ws + off);      off += (size_t)N_NODES*4;
    int*      cursor = (int*)(ws + off);      off += (size_t)N_NODES*4;
    size_t zero_bytes = (size_t)(ws + off - zero0);

    hipMemsetAsync(zero0, 0, zero_bytes, stream);

    // weight + input bf16 conversion + histogram
    prep<<<1569, 256, 0, stream>>>(
        edge_w, Wb, op_w, Wop, geo_w, Wgeo, skip_w, Wskip,
        child_feats, featsb, child_geo, geob, eidx, count);

    scan_offsets<<<1, 1024, 0, stream>>>(count, offs);

    fill_perm<<<N_EDGES/256, 256, 0, stream>>>(
        eidx, etoh, offs, cursor, from_p, to_p, efb_p);

    // encode + geo + skip via MFMA
    node_mfma<<<471, 256, 0, stream>>>(
        featsb, geob, child_exists, Wop, op_b, Wgeo, geo_b, Wskip, skip_b,
        cf_a, ipf0_m, pg_m, sg_m);

    // iter 1: MFMA messages + fused in-LDS segment max
    edge_mfma<1><<<N_EDGES/256, 512, 0, stream>>>(
        cf_a, from_p, to_p, efb_p, Wb, edge_b,
        offs, count, cf_bb, cf_b32, (int*)ipf1);

    // boundary nodes from atomic buffer -> bf16
    fixup<<<N_NODES/2, 256, 0, stream>>>(offs, count, cf_b32, cf_bb);

    // iter 2: only column max needed
    edge_mfma<0><<<N_EDGES/256, 512, 0, stream>>>(
        cf_bb, from_p, to_p, efb_p, Wb + 128*KPAD, edge_b + 128,
        offs, count, nullptr, nullptr, (int*)ipf2);

    heads<<<2, 128, 0, stream>>>(ipf0_m, ipf1, ipf2, sec_w, sec_b,
                                 pg_m, sg_m, sgeo_w, sgeo_b, gn_w, gn_b, out);
}

// Round 9
// 314.129 us; speedup vs baseline: 1.3102x; 1.1188x over previous
//
#include <hip/hip_runtime.h>

#define N_NODES 20000
#define N_EDGES 320000
#define HD 128
#define FIN 162      // 24 + 10 + 128
#define KE 260       // 2*H + ETN
#define KPAD 288     // edge K padded: 9 chunks of 32
#define KOP 192      // encode K padded: 6 chunks of 32
#define WSTR 296     // edge W LDS row stride (u16)
#define OSTR 200     // encode W LDS row stride (u16)
#define GSTR 136     // geo W LDS row stride (u16)
#define TSTR 136     // transpose row stride (u16)

typedef unsigned short u16;
typedef __attribute__((ext_vector_type(8))) short bf16x8;
typedef __attribute__((ext_vector_type(4))) float f32x4;

__device__ __forceinline__ float leaky(float x){ return x > 0.f ? x : 0.01f*x; }
__device__ __forceinline__ unsigned fmap(float f){
    unsigned u = __float_as_uint(f);
    return (u & 0x80000000u) ? ~u : (u | 0x80000000u);
}
__device__ __forceinline__ float funmap(unsigned u){
    return __uint_as_float((u & 0x80000000u) ? (u & 0x7fffffffu) : ~u);
}
__device__ __forceinline__ unsigned umax_(unsigned a, unsigned b){ return a > b ? a : b; }
__device__ __forceinline__ u16 f2bf(float x){
    unsigned b = __float_as_uint(x);
    return (u16)((b + 0x7fffu + ((b >> 16) & 1u)) >> 16);
}
__device__ __forceinline__ float bf2f(u16 u){
    return __uint_as_float(((unsigned)u) << 16);
}

// ---------------------------------------------------------------------------
// prep: fully-vectorized bf16 conversions + from-histogram
// blocks: [0,16) weights | [16,976) feats | [976,1616) geob | [1616,1936) hist
// ---------------------------------------------------------------------------
#define PB_W 16
#define PB_F 960
#define PB_G 640
#define PB_H 320
#define PREP_GRID (PB_W + PB_F + PB_G + PB_H)

__global__ __launch_bounds__(256) void prep(
    const float* __restrict__ edge_w, u16* __restrict__ Wb,
    const float* __restrict__ op_w,   u16* __restrict__ Wop,
    const float* __restrict__ geo_w,  u16* __restrict__ Wgeo,
    const float* __restrict__ skip_w, u16* __restrict__ Wskip,
    const float* __restrict__ feats,  u16* __restrict__ featsb,
    const float* __restrict__ geof,   u16* __restrict__ geob,
    const int* __restrict__ eidx, int* __restrict__ count)
{
    const int b = blockIdx.x, t = threadIdx.x;
    if (b < PB_W) {
        // 16384 uint4 of weights: edge(9216) | op(3072) | geo+skip(4096)
        for (int idx = b * 256 + t; idx < 16384; idx += PB_W * 256) {
            union { u16 us[8]; uint4 v; } pk;
            if (idx < 9216) {
                int layer = idx / 4608, rem = idx - layer * 4608;
                int h = rem / 36, j = rem - h * 36;
                const float* src = edge_w + (size_t)layer * 128 * KE + h * KE;
                #pragma unroll
                for (int kk = 0; kk < 8; ++kk) {
                    int k = j * 8 + kk;
                    pk.us[kk] = (k < KE) ? f2bf(src[k]) : (u16)0;
                }
                ((uint4*)Wb)[(size_t)layer * 128 * 36 + h * 36 + j] = pk.v;
            } else if (idx < 12288) {
                int rem = idx - 9216;
                int h = rem / 24, j = rem - h * 24;
                const float* src = op_w + h * FIN;
                #pragma unroll
                for (int kk = 0; kk < 8; ++kk) {
                    int k = j * 8 + kk;
                    pk.us[kk] = (k < FIN) ? f2bf(src[k]) : (u16)0;
                }
                ((uint4*)Wop)[h * 24 + j] = pk.v;
            } else {
                int rem = idx - 12288;
                int which = rem >> 11;
                int r2 = rem & 2047;
                const float4* src = (const float4*)((which ? skip_w : geo_w)) + r2 * 2;
                float4 a = src[0], c = src[1];
                pk.us[0]=f2bf(a.x); pk.us[1]=f2bf(a.y); pk.us[2]=f2bf(a.z); pk.us[3]=f2bf(a.w);
                pk.us[4]=f2bf(c.x); pk.us[5]=f2bf(c.y); pk.us[6]=f2bf(c.z); pk.us[7]=f2bf(c.w);
                ((uint4*)(which ? Wskip : Wgeo))[r2] = pk.v;
            }
        }
    } else if (b < PB_W + PB_F) {
        // featsb: 20000 rows x 24 uint4 = 480000
        for (int f = (b - PB_W) * 256 + t; f < N_NODES * 24; f += PB_F * 256) {
            int n = f / 24, j = f - n * 24;
            union { u16 us[8]; uint4 v; } pk;
            if (j < 20) {
                const float2* src = (const float2*)(feats + (size_t)n * FIN + j * 8);
                float2 p0 = src[0], p1 = src[1], p2 = src[2], p3 = src[3];
                pk.us[0]=f2bf(p0.x); pk.us[1]=f2bf(p0.y); pk.us[2]=f2bf(p1.x); pk.us[3]=f2bf(p1.y);
                pk.us[4]=f2bf(p2.x); pk.us[5]=f2bf(p2.y); pk.us[6]=f2bf(p3.x); pk.us[7]=f2bf(p3.y);
            } else if (j == 20) {
                float2 p = *(const float2*)(feats + (size_t)n * FIN + 160);
                pk.us[0]=f2bf(p.x); pk.us[1]=f2bf(p.y);
                pk.us[2]=pk.us[3]=pk.us[4]=pk.us[5]=pk.us[6]=pk.us[7]=0;
            } else {
                #pragma unroll
                for (int kk = 0; kk < 8; ++kk) pk.us[kk] = 0;
            }
            ((uint4*)featsb)[(size_t)n * 24 + j] = pk.v;
        }
    } else if (b < PB_W + PB_F + PB_G) {
        // geob: 320000 uint4 (aligned float4 source)
        for (int g = (b - PB_W - PB_F) * 256 + t; g < N_NODES * 16; g += PB_G * 256) {
            const float4* s = (const float4*)geof + (size_t)g * 2;
            float4 a = s[0], c = s[1];
            union { u16 us[8]; uint4 v; } pk;
            pk.us[0]=f2bf(a.x); pk.us[1]=f2bf(a.y); pk.us[2]=f2bf(a.z); pk.us[3]=f2bf(a.w);
            pk.us[4]=f2bf(c.x); pk.us[5]=f2bf(c.y); pk.us[6]=f2bf(c.z); pk.us[7]=f2bf(c.w);
            ((uint4*)geob)[g] = pk.v;
        }
    } else {
        for (int e = (b - PB_W - PB_F - PB_G) * 256 + t; e < N_EDGES; e += PB_H * 256)
            atomicAdd(&count[eidx[2 * e]], 1);
    }
}

// ---------------------------------------------------------------------------
__global__ __launch_bounds__(1024) void scan_offsets(
    const int* __restrict__ count, int* __restrict__ offset)
{
    __shared__ int part[1024];
    const int t = threadIdx.x;
    const int lo = t * 20;
    const int hi = min(lo + 20, N_NODES);
    int s = 0;
    for (int n = lo; n < hi; ++n) s += count[n];
    part[t] = s;
    __syncthreads();
    for (int d = 1; d < 1024; d <<= 1) {
        int v = (t >= d) ? part[t - d] : 0;
        __syncthreads();
        part[t] += v;
        __syncthreads();
    }
    int run = (t > 0) ? part[t - 1] : 0;
    for (int n = lo; n < hi; ++n) { offset[n] = run; run += count[n]; }
}

__global__ __launch_bounds__(256) void fill_perm(
    const int* __restrict__ eidx, const float* __restrict__ ef,
    const int* __restrict__ offset, int* __restrict__ cursor,
    int* __restrict__ from_p, int* __restrict__ to_p, uint2* __restrict__ efb_p)
{
    int e = blockIdx.x * 256 + threadIdx.x;
    int2 p = ((const int2*)eidx)[e];
    int pos = offset[p.x] + atomicAdd(&cursor[p.x], 1);
    from_p[pos] = p.x; to_p[pos] = p.y;
    float4 e4 = ((const float4*)ef)[e];
    efb_p[pos] = make_uint2(
        (unsigned)f2bf(e4.x) | ((unsigned)f2bf(e4.y) << 16),
        (unsigned)f2bf(e4.z) | ((unsigned)f2bf(e4.w) << 16));
}

// ---------------------------------------------------------------------------
// node MFMA: blocks [0,157) encode | [157,314) geo/pg | [314,471) skip/sg
// ---------------------------------------------------------------------------
__global__ __launch_bounds__(256) void node_mfma(
    const u16* __restrict__ featsb,   // [N,192] bf16
    const u16* __restrict__ geob,     // [N,128] bf16
    const float* __restrict__ exists,
    const u16* __restrict__ Wop, const float* __restrict__ op_b,
    const u16* __restrict__ Wgeo, const float* __restrict__ geo_b,
    const u16* __restrict__ Wskip, const float* __restrict__ skip_b,
    u16* __restrict__ cf_a,           // [N,128] bf16 out (encode only)
    unsigned* __restrict__ ipf0_m, unsigned* __restrict__ pg_m,
    unsigned* __restrict__ sg_m)
{
    __shared__ __align__(16) u16 smem[128 * OSTR];   // 51200 B
    __shared__ float ex_s[128];
    __shared__ unsigned colmax_s[128];

    const int b = blockIdx.x, t = threadIdx.x;
    const int mode = (b < 157) ? 0 : (b < 314) ? 1 : 2;
    const int bx = b - (mode == 0 ? 0 : mode == 1 ? 157 : 314);
    const int base = bx * 128;
    const int wave = t >> 6, l = t & 63;
    const int quad = l >> 4, lc = l & 15;
    const int R0 = (wave >> 1) * 64;
    const int C0 = (wave & 1) * 64;

    const u16* W = (mode == 0) ? Wop : (mode == 1) ? Wgeo : Wskip;
    const float* bias = (mode == 0) ? op_b : (mode == 1) ? geo_b : skip_b;
    unsigned* accout = (mode == 0) ? ipf0_m : (mode == 1) ? pg_m : sg_m;
    const int KW = (mode == 0) ? KOP : HD;
    const int SW = (mode == 0) ? OSTR : GSTR;
    const int NCH = (mode == 0) ? 6 : 4;
    const u16* A = (mode == 0) ? featsb : geob;

    {
        const int r = t >> 1, half = t & 1;
        const int nu4 = KW / 16;
        const uint4* src = (const uint4*)(W + (size_t)r * KW) + half * nu4;
        uint4* dst = (uint4*)(smem + r * SW) + half * nu4;
        for (int i = 0; i < nu4; ++i) dst[i] = src[i];
    }
    if (t < 128) {
        int n = base + t; if (n >= N_NODES) n = N_NODES - 1;
        ex_s[t] = exists[n];
        colmax_s[t] = 0u;
    }
    __syncthreads();

    f32x4 acc[4][4];
    #pragma unroll
    for (int i = 0; i < 4; ++i)
        #pragma unroll
        for (int j = 0; j < 4; ++j) acc[i][j] = (f32x4){0.f, 0.f, 0.f, 0.f};

    int nd[4];
    #pragma unroll
    for (int ti = 0; ti < 4; ++ti) {
        int n = base + R0 + ti * 16 + lc;
        nd[ti] = (n < N_NODES) ? n : N_NODES - 1;
    }

    for (int c = 0; c < NCH; ++c) {
        bf16x8 af[4], bfr[4];
        #pragma unroll
        for (int ti = 0; ti < 4; ++ti)
            af[ti] = *(const bf16x8*)(A + (size_t)nd[ti] * KW + c * 32 + quad * 8);
        #pragma unroll
        for (int tj = 0; tj < 4; ++tj)
            bfr[tj] = *(const bf16x8*)(smem + (C0 + tj * 16 + lc) * SW + c * 32 + quad * 8);
        #pragma unroll
        for (int ti = 0; ti < 4; ++ti)
            #pragma unroll
            for (int tj = 0; tj < 4; ++tj)
                acc[ti][tj] = __builtin_amdgcn_mfma_f32_16x16x32_bf16(
                    af[ti], bfr[tj], acc[ti][tj], 0, 0, 0);
    }

    #pragma unroll
    for (int tj = 0; tj < 4; ++tj) {
        const int col = C0 + tj * 16 + lc;
        const float bc = bias[col];
        unsigned mx = 0u;
        #pragma unroll
        for (int ti = 0; ti < 4; ++ti) {
            #pragma unroll
            for (int r = 0; r < 4; ++r) {
                int row = R0 + ti * 16 + quad * 4 + r;
                float x = (acc[ti][tj][r] + bc) * ex_s[row];
                acc[ti][tj][r] = x;
                mx = umax_(mx, fmap(x));
            }
        }
        atomicMax(&colmax_s[col], mx);
    }
    __syncthreads();
    if (t < 128) atomicMax(&accout[t], colmax_s[t]);

    if (mode == 0) {
        #pragma unroll
        for (int ti = 0; ti < 4; ++ti)
            #pragma unroll
            for (int tj = 0; tj < 4; ++tj) {
                const int col = C0 + tj * 16 + lc;
                #pragma unroll
                for (int r = 0; r < 4; ++r)
                    smem[(R0 + ti * 16 + quad * 4 + r) * TSTR + col] = f2bf(acc[ti][tj][r]);
            }
        __syncthreads();
        #pragma unroll
        for (int i = 0; i < 8; ++i) {
            int idx = t + i * 256;
            int row = idx >> 4, c16 = idx & 15;
            int n = base + row;
            if (n < N_NODES) {
                uint4 v = *(const uint4*)(smem + row * TSTR + c16 * 8);
                *(uint4*)(cf_a + (size_t)n * HD + c16 * 8) = v;
            }
        }
    }
}

// ---------------------------------------------------------------------------
// Barrier-free MFMA edge pass (see round 7/8 notes)
// ---------------------------------------------------------------------------
template<int REDUCE>
__global__ __launch_bounds__(512, 4) void edge_mfma(
    const u16* __restrict__ cfb,
    const int* __restrict__ from_p,
    const int* __restrict__ to_p,
    const uint2* __restrict__ efb_p,
    const u16* __restrict__ Wb,
    const float* __restrict__ bias,
    const int* __restrict__ offs,
    const int* __restrict__ cnt,
    u16* __restrict__ cf_bb,
    float* __restrict__ cf_b32,
    int* __restrict__ ipf_out)
{
    __shared__ __align__(16) u16 smem[128 * WSTR];
    __shared__ int colmax_s[128];

    const int t    = threadIdx.x;
    const int base = blockIdx.x * 256;
    const int wave = t >> 6, l = t & 63;
    const int quad = l >> 4, lc = l & 15;
    const int R0 = (wave >> 1) * 64;
    const int C0 = (wave & 1) * 64;

    {
        const int r = t >> 2, q = t & 3;
        const uint4* src = (const uint4*)(Wb + r * KPAD + q * 72);
        uint4* dst = (uint4*)(smem + r * WSTR + q * 72);
        #pragma unroll
        for (int i = 0; i < 9; ++i) dst[i] = src[i];
    }
    if (t < 128) colmax_s[t] = 0;

    int nf[4], nt[4]; uint2 efr[4];
    #pragma unroll
    for (int ti = 0; ti < 4; ++ti) {
        int e = base + R0 + ti * 16 + lc;
        nf[ti]  = from_p[e];
        nt[ti]  = to_p[e];
        efr[ti] = efb_p[e];
    }
    __syncthreads();

    f32x4 acc[4][4];
    #pragma unroll
    for (int i = 0; i < 4; ++i)
        #pragma unroll
        for (int j = 0; j < 4; ++j) acc[i][j] = (f32x4){0.f, 0.f, 0.f, 0.f};

    #pragma unroll
    for (int c = 0; c < 8; ++c) {
        bf16x8 af[4], bfr[4];
        #pragma unroll
        for (int ti = 0; ti < 4; ++ti) {
            int node = (c < 4) ? nf[ti] : nt[ti];
            af[ti] = *(const bf16x8*)(cfb + node * HD + (c & 3) * 32 + quad * 8);
        }
        #pragma unroll
        for (int tj = 0; tj < 4; ++tj)
            bfr[tj] = *(const bf16x8*)(smem + (C0 + tj * 16 + lc) * WSTR + c * 32 + quad * 8);
        #pragma unroll
        for (int ti = 0; ti < 4; ++ti)
            #pragma unroll
            for (int tj = 0; tj < 4; ++tj)
                acc[ti][tj] = __builtin_amdgcn_mfma_f32_16x16x32_bf16(
                    af[ti], bfr[tj], acc[ti][tj], 0, 0, 0);
    }
    {
        bf16x8 af[4], bfr[4];
        #pragma unroll
        for (int ti = 0; ti < 4; ++ti) {
            union { bf16x8 v; unsigned u[4]; } p;
            p.u[0] = efr[ti].x; p.u[1] = efr[ti].y; p.u[2] = 0u; p.u[3] = 0u;
            union { bf16x8 v; unsigned u[4]; } z;
            z.u[0] = z.u[1] = z.u[2] = z.u[3] = 0u;
            af[ti] = (quad == 0) ? p.v : z.v;
        }
        #pragma unroll
        for (int tj = 0; tj < 4; ++tj)
            bfr[tj] = *(const bf16x8*)(smem + (C0 + tj * 16 + lc) * WSTR + 8 * 32 + quad * 8);
        #pragma unroll
        for (int ti = 0; ti < 4; ++ti)
            #pragma unroll
            for (int tj = 0; tj < 4; ++tj)
                acc[ti][tj] = __builtin_amdgcn_mfma_f32_16x16x32_bf16(
                    af[ti], bfr[tj], acc[ti][tj], 0, 0, 0);
    }

    #pragma unroll
    for (int tj = 0; tj < 4; ++tj) {
        const int col = C0 + tj * 16 + lc;
        const float bc = bias[col];
        float mx = 0.f;
        #pragma unroll
        for (int ti = 0; ti < 4; ++ti) {
            #pragma unroll
            for (int r = 0; r < 4; ++r) {
                float x = leaky(acc[ti][tj][r] + bc);
                acc[ti][tj][r] = x;
                mx = fmaxf(mx, x);
            }
        }
        atomicMax(&colmax_s[col], __float_as_int(mx));
    }
    __syncthreads();
    if (t < 128) atomicMax(&ipf_out[t], colmax_s[t]);

    if (REDUCE) {
        #pragma unroll
        for (int ti = 0; ti < 4; ++ti)
            #pragma unroll
            for (int tj = 0; tj < 4; ++tj) {
                const int col = C0 + tj * 16 + lc;
                #pragma unroll
                for (int r = 0; r < 4; ++r)
                    smem[(R0 + ti * 16 + quad * 4 + r) * TSTR + col] = f2bf(acc[ti][tj][r]);
            }
        __syncthreads();
        const int nfirst = from_p[base];
        const int nlast  = from_p[base + 255];
        const int ch = t & 127;
        for (int n = nfirst + (t >> 7); n <= nlast; n += 4) {
            int o = offs[n], c = cnt[n];
            int lo = o - base, hi = o + c - base;
            int lo2 = lo > 0 ? lo : 0;
            int hi2 = hi < 256 ? hi : 256;
            if (lo2 >= hi2) continue;
            float m = 0.f;
            for (int r = lo2; r < hi2; ++r)
                m = fmaxf(m, bf2f(smem[r * TSTR + ch]));
            if (lo >= 0 && hi <= 256)
                cf_bb[(size_t)n * HD + ch] = f2bf(m);
            else
                atomicMax((int*)&cf_b32[(size_t)n * HD + ch], __float_as_int(m));
        }
    }
}

// ---------------------------------------------------------------------------
__global__ __launch_bounds__(256) void fixup(
    const int* __restrict__ offs, const int* __restrict__ cnt,
    const float* __restrict__ cf_b32, u16* __restrict__ cf_bb)
{
    const int n = blockIdx.x * 2 + (threadIdx.x >> 7);
    const int ch = threadIdx.x & 127;
    int o = offs[n], c = cnt[n];
    if (c > 0 && (o >> 8) != ((o + c - 1) >> 8))
        cf_bb[(size_t)n * HD + ch] = f2bf(cf_b32[(size_t)n * HD + ch]);
}

// ---------------------------------------------------------------------------
__global__ __launch_bounds__(128) void heads(
    const unsigned* __restrict__ ipf0_m,
    const float* __restrict__ ipf1, const float* __restrict__ ipf2,
    const float* __restrict__ secW, const float* __restrict__ secB,
    const unsigned* __restrict__ pg_m, const unsigned* __restrict__ sg_m,
    const float* __restrict__ geoW, const float* __restrict__ geoB,
    const float* __restrict__ gnw, const float* __restrict__ gnb,
    float* __restrict__ out)
{
    const int t = threadIdx.x;
    if (blockIdx.x == 0) {
        __shared__ float s[384];
        s[t]       = funmap(ipf0_m[t]);
        s[128 + t] = ipf1[t];
        s[256 + t] = ipf2[t];
        __syncthreads();
        float acc = secB[t];
        #pragma unroll 4
        for (int k = 0; k < 384; ++k) acc = fmaf(s[k], secW[t*384 + k], acc);
        out[t] = leaky(acc);
    } else {
        __shared__ float pg[128];
        __shared__ float tt[128];
        pg[t] = leaky(funmap(pg_m[t]));
        float sg = leaky(funmap(sg_m[t]));
        __syncthreads();
        float acc = geoB[t];
        #pragma unroll 4
        for (int k = 0; k < 128; ++k) acc = fmaf(pg[k], geoW[t*128 + k], acc);
        tt[t] = acc;
        __syncthreads();
        const int g = (t >> 3) << 3;
        float mu = 0.f, m2 = 0.f;
        #pragma unroll
        for (int q = 0; q < 8; ++q) { float x = tt[g + q]; mu += x; m2 += x*x; }
        mu *= 0.125f;
        m2 = m2 * 0.125f - mu * mu;
        float xn = (acc - mu) * rsqrtf(m2 + 1e-5f);
        out[128 + t] = leaky(sg + xn * gnw[t] + gnb[t]);
    }
}

// ---------------------------------------------------------------------------
extern "C" void kernel_launch(void* const* d_in, const int* in_sizes, int n_in,
                              void* d_out, int out_size, void* d_ws, size_t ws_size,
                              hipStream_t stream)
{
    const float* child_feats  = (const float*)d_in[0];
    const float* child_geo    = (const float*)d_in[1];
    const float* child_exists = (const float*)d_in[2];
    const float* etoh         = (const float*)d_in[3];
    const int*   eidx         = (const int*)  d_in[4];
    const float* op_w   = (const float*)d_in[5];
    const float* op_b   = (const float*)d_in[6];
    const float* sec_w  = (const float*)d_in[7];
    const float* sec_b  = (const float*)d_in[8];
    const float* edge_w = (const float*)d_in[9];
    const float* edge_b = (const float*)d_in[10];
    const float* geo_w  = (const float*)d_in[11];
    const float* geo_b  = (const float*)d_in[12];
    const float* sgeo_w = (const float*)d_in[13];
    const float* sgeo_b = (const float*)d_in[14];
    const float* gn_w   = (const float*)d_in[15];
    const float* gn_b   = (const float*)d_in[16];
    const float* skip_w = (const float*)d_in[17];
    const float* skip_b = (const float*)d_in[18];
    float* out = (float*)d_out;

    // workspace layout (all offsets 16B aligned)
    char* ws = (char*)d_ws;
    size_t off = 0;
    u16*   cf_a   = (u16*)(ws + off);   off += (size_t)N_NODES*HD*2;     // 5.12 MB
    u16*   featsb = (u16*)(ws + off);   off += (size_t)N_NODES*KOP*2;    // 7.68 MB
    u16*   geob   = (u16*)(ws + off);   off += (size_t)N_NODES*HD*2;     // 5.12 MB
    u16*   Wb     = (u16*)(ws + off);   off += (size_t)2*128*KPAD*2;     // 147 KB
    u16*   Wop    = (u16*)(ws + off);   off += (size_t)128*KOP*2;        // 49 KB
    u16*   Wgeo   = (u16*)(ws + off);   off += (size_t)128*128*2;        // 32 KB
    u16*   Wskip  = (u16*)(ws + off);   off += (size_t)128*128*2;        // 32 KB
    int*   from_p = (int*)(ws + off);   off += (size_t)N_EDGES*4;        // 1.28 MB
    int*   to_p   = (int*)(ws + off);   off += (size_t)N_EDGES*4;        // 1.28 MB
    uint2* efb_p  = (uint2*)(ws + off); off += (size_t)N_EDGES*8;        // 2.56 MB
    int*   offs   = (int*)(ws + off);   off += (size_t)N_NODES*4;        // 80 KB
    char*  zero0  = ws + off;
    u16*   cf_bb  = (u16*)(ws + off);         off += (size_t)N_NODES*HD*2;  // 5.12 MB
    float* cf_b32 = (float*)(ws + off);       off += (size_t)N_NODES*HD*4;  // 10.24 MB
    unsigned* ipf0_m = (unsigned*)(ws + off); off += 128*4;
    float*    ipf1   = (float*)(ws + off);    off += 128*4;
    float*    ipf2   = (float*)(ws + off);    off += 128*4;
    unsigned* pg_m   = (unsigned*)(ws + off); off += 128*4;
    unsigned* sg_m   = (unsigned*)(ws + off); off += 128*4;
    int*      count  = (int*)(ws + off);      off += (size_t)N_NODES*4;
    int*      cursor = (int*)(ws + off);      off += (size_t)N_NODES*4;
    size_t zero_bytes = (size_t)(ws + off - zero0);

    hipMemsetAsync(zero0, 0, zero_bytes, stream);

    // vectorized conversions + histogram
    prep<<<PREP_GRID, 256, 0, stream>>>(
        edge_w, Wb, op_w, Wop, geo_w, Wgeo, skip_w, Wskip,
        child_feats, featsb, child_geo, geob, eidx, count);

    scan_offsets<<<1, 1024, 0, stream>>>(count, offs);

    fill_perm<<<N_EDGES/256, 256, 0, stream>>>(
        eidx, etoh, offs, cursor, from_p, to_p, efb_p);

    // encode + geo + skip via MFMA
    node_mfma<<<471, 256, 0, stream>>>(
        featsb, geob, child_exists, Wop, op_b, Wgeo, geo_b, Wskip, skip_b,
        cf_a, ipf0_m, pg_m, sg_m);

    // iter 1: MFMA messages + fused in-LDS segment max
    edge_mfma<1><<<N_EDGES/256, 512, 0, stream>>>(
        cf_a, from_p, to_p, efb_p, Wb, edge_b,
        offs, count, cf_bb, cf_b32, (int*)ipf1);

    // boundary nodes from atomic buffer -> bf16
    fixup<<<N_NODES/2, 256, 0, stream>>>(offs, count, cf_b32, cf_bb);

    // iter 2: only column max needed
    edge_mfma<0><<<N_EDGES/256, 512, 0, stream>>>(
        cf_bb, from_p, to_p, efb_p, Wb + 128*KPAD, edge_b + 128,
        offs, count, nullptr, nullptr, (int*)ipf2);

    heads<<<2, 128, 0, stream>>>(ipf0_m, ipf1, ipf2, sec_w, sec_b,
                                 pg_m, sg_m, sgeo_w, sgeo_b, gn_w, gn_b, out);
}

// Round 10
// 295.174 us; speedup vs baseline: 1.3943x; 1.0642x over previous
//
#include <hip/hip_runtime.h>

#define N_NODES 20000
#define N_EDGES 320000
#define HD 128
#define FIN 162      // 24 + 10 + 128
#define KE 260       // 2*H + ETN
#define KPAD 288     // edge K padded: 9 chunks of 32
#define KOP 192      // encode K padded: 6 chunks of 32
#define WSTR 296     // edge W LDS row stride (u16): 592B -> 2-way max on b128 reads
#define OSTR 200     // encode W LDS row stride (u16)
#define GSTR 136     // geo W LDS row stride (u16)
#define TSTR 136     // node transpose row stride (u16)
#define XSTR 72      // edge transpose row stride (u16): 64 ch + 8 pad

typedef unsigned short u16;
typedef __attribute__((ext_vector_type(8))) short bf16x8;
typedef __attribute__((ext_vector_type(4))) float f32x4;

__device__ __forceinline__ float leaky(float x){ return x > 0.f ? x : 0.01f*x; }
__device__ __forceinline__ unsigned fmap(float f){
    unsigned u = __float_as_uint(f);
    return (u & 0x80000000u) ? ~u : (u | 0x80000000u);
}
__device__ __forceinline__ float funmap(unsigned u){
    return __uint_as_float((u & 0x80000000u) ? (u & 0x7fffffffu) : ~u);
}
__device__ __forceinline__ unsigned umax_(unsigned a, unsigned b){ return a > b ? a : b; }
__device__ __forceinline__ u16 f2bf(float x){
    unsigned b = __float_as_uint(x);
    return (u16)((b + 0x7fffu + ((b >> 16) & 1u)) >> 16);
}
__device__ __forceinline__ float bf2f(u16 u){
    return __uint_as_float(((unsigned)u) << 16);
}

// ---------------------------------------------------------------------------
// prep: fully-vectorized bf16 conversions + from-histogram
// ---------------------------------------------------------------------------
#define PB_W 16
#define PB_F 960
#define PB_G 640
#define PB_H 320
#define PREP_GRID (PB_W + PB_F + PB_G + PB_H)

__global__ __launch_bounds__(256) void prep(
    const float* __restrict__ edge_w, u16* __restrict__ Wb,
    const float* __restrict__ op_w,   u16* __restrict__ Wop,
    const float* __restrict__ geo_w,  u16* __restrict__ Wgeo,
    const float* __restrict__ skip_w, u16* __restrict__ Wskip,
    const float* __restrict__ feats,  u16* __restrict__ featsb,
    const float* __restrict__ geof,   u16* __restrict__ geob,
    const int* __restrict__ eidx, int* __restrict__ count)
{
    const int b = blockIdx.x, t = threadIdx.x;
    if (b < PB_W) {
        for (int idx = b * 256 + t; idx < 16384; idx += PB_W * 256) {
            union { u16 us[8]; uint4 v; } pk;
            if (idx < 9216) {
                int layer = idx / 4608, rem = idx - layer * 4608;
                int h = rem / 36, j = rem - h * 36;
                const float* src = edge_w + (size_t)layer * 128 * KE + h * KE;
                #pragma unroll
                for (int kk = 0; kk < 8; ++kk) {
                    int k = j * 8 + kk;
                    pk.us[kk] = (k < KE) ? f2bf(src[k]) : (u16)0;
                }
                ((uint4*)Wb)[(size_t)layer * 128 * 36 + h * 36 + j] = pk.v;
            } else if (idx < 12288) {
                int rem = idx - 9216;
                int h = rem / 24, j = rem - h * 24;
                const float* src = op_w + h * FIN;
                #pragma unroll
                for (int kk = 0; kk < 8; ++kk) {
                    int k = j * 8 + kk;
                    pk.us[kk] = (k < FIN) ? f2bf(src[k]) : (u16)0;
                }
                ((uint4*)Wop)[h * 24 + j] = pk.v;
            } else {
                int rem = idx - 12288;
                int which = rem >> 11;
                int r2 = rem & 2047;
                const float4* src = (const float4*)((which ? skip_w : geo_w)) + r2 * 2;
                float4 a = src[0], c = src[1];
                pk.us[0]=f2bf(a.x); pk.us[1]=f2bf(a.y); pk.us[2]=f2bf(a.z); pk.us[3]=f2bf(a.w);
                pk.us[4]=f2bf(c.x); pk.us[5]=f2bf(c.y); pk.us[6]=f2bf(c.z); pk.us[7]=f2bf(c.w);
                ((uint4*)(which ? Wskip : Wgeo))[r2] = pk.v;
            }
        }
    } else if (b < PB_W + PB_F) {
        for (int f = (b - PB_W) * 256 + t; f < N_NODES * 24; f += PB_F * 256) {
            int n = f / 24, j = f - n * 24;
            union { u16 us[8]; uint4 v; } pk;
            if (j < 20) {
                const float2* src = (const float2*)(feats + (size_t)n * FIN + j * 8);
                float2 p0 = src[0], p1 = src[1], p2 = src[2], p3 = src[3];
                pk.us[0]=f2bf(p0.x); pk.us[1]=f2bf(p0.y); pk.us[2]=f2bf(p1.x); pk.us[3]=f2bf(p1.y);
                pk.us[4]=f2bf(p2.x); pk.us[5]=f2bf(p2.y); pk.us[6]=f2bf(p3.x); pk.us[7]=f2bf(p3.y);
            } else if (j == 20) {
                float2 p = *(const float2*)(feats + (size_t)n * FIN + 160);
                pk.us[0]=f2bf(p.x); pk.us[1]=f2bf(p.y);
                pk.us[2]=pk.us[3]=pk.us[4]=pk.us[5]=pk.us[6]=pk.us[7]=0;
            } else {
                #pragma unroll
                for (int kk = 0; kk < 8; ++kk) pk.us[kk] = 0;
            }
            ((uint4*)featsb)[(size_t)n * 24 + j] = pk.v;
        }
    } else if (b < PB_W + PB_F + PB_G) {
        for (int g = (b - PB_W - PB_F) * 256 + t; g < N_NODES * 16; g += PB_G * 256) {
            const float4* s = (const float4*)geof + (size_t)g * 2;
            float4 a = s[0], c = s[1];
            union { u16 us[8]; uint4 v; } pk;
            pk.us[0]=f2bf(a.x); pk.us[1]=f2bf(a.y); pk.us[2]=f2bf(a.z); pk.us[3]=f2bf(a.w);
            pk.us[4]=f2bf(c.x); pk.us[5]=f2bf(c.y); pk.us[6]=f2bf(c.z); pk.us[7]=f2bf(c.w);
            ((uint4*)geob)[g] = pk.v;
        }
    } else {
        for (int e = (b - PB_W - PB_F - PB_G) * 256 + t; e < N_EDGES; e += PB_H * 256)
            atomicAdd(&count[eidx[2 * e]], 1);
    }
}

// ---------------------------------------------------------------------------
__global__ __launch_bounds__(1024) void scan_offsets(
    const int* __restrict__ count, int* __restrict__ offset)
{
    __shared__ int part[1024];
    const int t = threadIdx.x;
    const int lo = t * 20;
    const int hi = min(lo + 20, N_NODES);
    int s = 0;
    for (int n = lo; n < hi; ++n) s += count[n];
    part[t] = s;
    __syncthreads();
    for (int d = 1; d < 1024; d <<= 1) {
        int v = (t >= d) ? part[t - d] : 0;
        __syncthreads();
        part[t] += v;
        __syncthreads();
    }
    int run = (t > 0) ? part[t - 1] : 0;
    for (int n = lo; n < hi; ++n) { offset[n] = run; run += count[n]; }
}

// ---------------------------------------------------------------------------
// mid: blocks [0,1250) fill_perm | [1250,1721) node MFMA
// ---------------------------------------------------------------------------
__global__ __launch_bounds__(256) void mid(
    const int* __restrict__ eidx, const float* __restrict__ ef,
    const int* __restrict__ offset, int* __restrict__ cursor,
    int* __restrict__ from_p, int* __restrict__ to_p, uint2* __restrict__ efb_p,
    const u16* __restrict__ featsb, const u16* __restrict__ geob,
    const float* __restrict__ exists,
    const u16* __restrict__ Wop, const float* __restrict__ op_b,
    const u16* __restrict__ Wgeo, const float* __restrict__ geo_b,
    const u16* __restrict__ Wskip, const float* __restrict__ skip_b,
    u16* __restrict__ cf_a,
    unsigned* __restrict__ ipf0_m, unsigned* __restrict__ pg_m,
    unsigned* __restrict__ sg_m)
{
    __shared__ __align__(16) u16 smem[128 * OSTR];   // 51200 B
    __shared__ float ex_s[128];
    __shared__ unsigned colmax_s[128];

    const int blk = blockIdx.x, t = threadIdx.x;
    if (blk < 1250) {
        int e = blk * 256 + t;
        int2 p = ((const int2*)eidx)[e];
        int pos = offset[p.x] + atomicAdd(&cursor[p.x], 1);
        from_p[pos] = p.x; to_p[pos] = p.y;
        float4 e4 = ((const float4*)ef)[e];
        efb_p[pos] = make_uint2(
            (unsigned)f2bf(e4.x) | ((unsigned)f2bf(e4.y) << 16),
            (unsigned)f2bf(e4.z) | ((unsigned)f2bf(e4.w) << 16));
        return;
    }
    const int b = blk - 1250;
    const int mode = (b < 157) ? 0 : (b < 314) ? 1 : 2;
    const int bx = b - (mode == 0 ? 0 : mode == 1 ? 157 : 314);
    const int base = bx * 128;
    const int wave = t >> 6, l = t & 63;
    const int quad = l >> 4, lc = l & 15;
    const int R0 = (wave >> 1) * 64;
    const int C0 = (wave & 1) * 64;

    const u16* W = (mode == 0) ? Wop : (mode == 1) ? Wgeo : Wskip;
    const float* bias = (mode == 0) ? op_b : (mode == 1) ? geo_b : skip_b;
    unsigned* accout = (mode == 0) ? ipf0_m : (mode == 1) ? pg_m : sg_m;
    const int KW = (mode == 0) ? KOP : HD;
    const int SW = (mode == 0) ? OSTR : GSTR;
    const int NCH = (mode == 0) ? 6 : 4;
    const u16* A = (mode == 0) ? featsb : geob;

    {
        const int r = t >> 1, half = t & 1;
        const int nu4 = KW / 16;
        const uint4* src = (const uint4*)(W + (size_t)r * KW) + half * nu4;
        uint4* dst = (uint4*)(smem + r * SW) + half * nu4;
        for (int i = 0; i < nu4; ++i) dst[i] = src[i];
    }
    if (t < 128) {
        int n = base + t; if (n >= N_NODES) n = N_NODES - 1;
        ex_s[t] = exists[n];
        colmax_s[t] = 0u;
    }
    __syncthreads();

    f32x4 acc[4][4];
    #pragma unroll
    for (int i = 0; i < 4; ++i)
        #pragma unroll
        for (int j = 0; j < 4; ++j) acc[i][j] = (f32x4){0.f, 0.f, 0.f, 0.f};

    int nd[4];
    #pragma unroll
    for (int ti = 0; ti < 4; ++ti) {
        int n = base + R0 + ti * 16 + lc;
        nd[ti] = (n < N_NODES) ? n : N_NODES - 1;
    }

    for (int c = 0; c < NCH; ++c) {
        bf16x8 af[4], bfr[4];
        #pragma unroll
        for (int ti = 0; ti < 4; ++ti)
            af[ti] = *(const bf16x8*)(A + (size_t)nd[ti] * KW + c * 32 + quad * 8);
        #pragma unroll
        for (int tj = 0; tj < 4; ++tj)
            bfr[tj] = *(const bf16x8*)(smem + (C0 + tj * 16 + lc) * SW + c * 32 + quad * 8);
        #pragma unroll
        for (int ti = 0; ti < 4; ++ti)
            #pragma unroll
            for (int tj = 0; tj < 4; ++tj)
                acc[ti][tj] = __builtin_amdgcn_mfma_f32_16x16x32_bf16(
                    af[ti], bfr[tj], acc[ti][tj], 0, 0, 0);
    }

    #pragma unroll
    for (int tj = 0; tj < 4; ++tj) {
        const int col = C0 + tj * 16 + lc;
        const float bc = bias[col];
        unsigned mx = 0u;
        #pragma unroll
        for (int ti = 0; ti < 4; ++ti) {
            #pragma unroll
            for (int r = 0; r < 4; ++r) {
                int row = R0 + ti * 16 + quad * 4 + r;
                float x = (acc[ti][tj][r] + bc) * ex_s[row];
                acc[ti][tj][r] = x;
                mx = umax_(mx, fmap(x));
            }
        }
        atomicMax(&colmax_s[col], mx);
    }
    __syncthreads();
    if (t < 128) atomicMax(&accout[t], colmax_s[t]);

    if (mode == 0) {
        #pragma unroll
        for (int ti = 0; ti < 4; ++ti)
            #pragma unroll
            for (int tj = 0; tj < 4; ++tj) {
                const int col = C0 + tj * 16 + lc;
                #pragma unroll
                for (int r = 0; r < 4; ++r)
                    smem[(R0 + ti * 16 + quad * 4 + r) * TSTR + col] = f2bf(acc[ti][tj][r]);
            }
        __syncthreads();
        #pragma unroll
        for (int i = 0; i < 8; ++i) {
            int idx = t + i * 256;
            int row = idx >> 4, c16 = idx & 15;
            int n = base + row;
            if (n < N_NODES) {
                uint4 v = *(const uint4*)(smem + row * TSTR + c16 * 8);
                *(uint4*)(cf_a + (size_t)n * HD + c16 * 8) = v;
            }
        }
    }
}

// ---------------------------------------------------------------------------
// Column-split barrier-free MFMA edge pass:
// block = 512 edges x 64 channels (half = blockIdx.x & 1); 8 waves stacked
// along rows (64 edges each). W half (64 rows x 288) in LDS = 37.9 KB ->
// 4 blocks/CU. A fragments: direct global gather. K = 9x32, no K barriers.
// REDUCE: 2-phase (256-row) LDS transpose + in-LDS segment max.
// ---------------------------------------------------------------------------
template<int REDUCE>
__global__ __launch_bounds__(512, 4) void edge_mfma(
    const u16* __restrict__ cfb,
    const int* __restrict__ from_p,
    const int* __restrict__ to_p,
    const uint2* __restrict__ efb_p,
    const u16* __restrict__ Wb,
    const float* __restrict__ bias,
    const int* __restrict__ offs,
    const int* __restrict__ cnt,
    u16* __restrict__ cf_bb,
    float* __restrict__ cf_b32,
    int* __restrict__ ipf_out)
{
    __shared__ __align__(16) u16 smem[64 * WSTR];   // 37888 B (W half; reused 256xXSTR)
    __shared__ int colmax_s[64];

    const int t    = threadIdx.x;
    const int tile = blockIdx.x >> 1;
    const int half = blockIdx.x & 1;
    const int base = tile * 512;                // 625 tiles exact
    const int wave = t >> 6, l = t & 63;
    const int quad = l >> 4, lc = l & 15;
    const int R0 = wave * 64;
    const int C0 = half * 64;

    // preload W rows [C0, C0+64): 64 x 36 uint4
    for (int idx = t; idx < 64 * 36; idx += 512) {
        int r = idx / 36, j = idx - r * 36;
        ((uint4*)(smem + r * WSTR))[j] = ((const uint4*)(Wb + (size_t)(C0 + r) * KPAD))[j];
    }
    if (t < 64) colmax_s[t] = 0;

    int nf[4], nt[4]; uint2 efr[4];
    #pragma unroll
    for (int ti = 0; ti < 4; ++ti) {
        int e = base + R0 + ti * 16 + lc;
        nf[ti]  = from_p[e];
        nt[ti]  = to_p[e];
        efr[ti] = efb_p[e];
    }
    __syncthreads();   // W resident

    f32x4 acc[4][4];
    #pragma unroll
    for (int i = 0; i < 4; ++i)
        #pragma unroll
        for (int j = 0; j < 4; ++j) acc[i][j] = (f32x4){0.f, 0.f, 0.f, 0.f};

    #pragma unroll
    for (int c = 0; c < 8; ++c) {
        bf16x8 af[4], bfr[4];
        #pragma unroll
        for (int ti = 0; ti < 4; ++ti) {
            int node = (c < 4) ? nf[ti] : nt[ti];
            af[ti] = *(const bf16x8*)(cfb + node * HD + (c & 3) * 32 + quad * 8);
        }
        #pragma unroll
        for (int tj = 0; tj < 4; ++tj)
            bfr[tj] = *(const bf16x8*)(smem + (tj * 16 + lc) * WSTR + c * 32 + quad * 8);
        #pragma unroll
        for (int ti = 0; ti < 4; ++ti)
            #pragma unroll
            for (int tj = 0; tj < 4; ++tj)
                acc[ti][tj] = __builtin_amdgcn_mfma_f32_16x16x32_bf16(
                    af[ti], bfr[tj], acc[ti][tj], 0, 0, 0);
    }
    {   // chunk 8: edge-type features
        bf16x8 af[4], bfr[4];
        #pragma unroll
        for (int ti = 0; ti < 4; ++ti) {
            union { bf16x8 v; unsigned u[4]; } p;
            p.u[0] = efr[ti].x; p.u[1] = efr[ti].y; p.u[2] = 0u; p.u[3] = 0u;
            union { bf16x8 v; unsigned u[4]; } z;
            z.u[0] = z.u[1] = z.u[2] = z.u[3] = 0u;
            af[ti] = (quad == 0) ? p.v : z.v;
        }
        #pragma unroll
        for (int tj = 0; tj < 4; ++tj)
            bfr[tj] = *(const bf16x8*)(smem + (tj * 16 + lc) * WSTR + 8 * 32 + quad * 8);
        #pragma unroll
        for (int ti = 0; ti < 4; ++ti)
            #pragma unroll
            for (int tj = 0; tj < 4; ++tj)
                acc[ti][tj] = __builtin_amdgcn_mfma_f32_16x16x32_bf16(
                    af[ti], bfr[tj], acc[ti][tj], 0, 0, 0);
    }

    // bias + leaky; per-channel block max (64 channels of this half)
    #pragma unroll
    for (int tj = 0; tj < 4; ++tj) {
        const int cl = tj * 16 + lc;
        const float bc = bias[C0 + cl];
        float mx = 0.f;
        #pragma unroll
        for (int ti = 0; ti < 4; ++ti) {
            #pragma unroll
            for (int r = 0; r < 4; ++r) {
                float x = leaky(acc[ti][tj][r] + bc);
                acc[ti][tj][r] = x;
                mx = fmaxf(mx, x);
            }
        }
        atomicMax(&colmax_s[cl], __float_as_int(mx));
    }
    __syncthreads();   // colmax done; W reads drained (smem reusable)
    if (t < 64) atomicMax(&ipf_out[C0 + t], colmax_s[t]);

    if (REDUCE) {
        const int ch = t & 63;
        #pragma unroll
        for (int ph = 0; ph < 2; ++ph) {
            if ((R0 >> 8) == ph) {
                const int rb = R0 & 255;
                #pragma unroll
                for (int ti = 0; ti < 4; ++ti)
                    #pragma unroll
                    for (int tj = 0; tj < 4; ++tj) {
                        const int cl = tj * 16 + lc;
                        #pragma unroll
                        for (int r = 0; r < 4; ++r)
                            smem[(rb + ti * 16 + quad * 4 + r) * XSTR + cl]
                                = f2bf(acc[ti][tj][r]);
                    }
            }
            __syncthreads();
            const int wb = base + ph * 256;
            const int nfirst = from_p[wb];
            const int nlast  = from_p[wb + 255];
            for (int n = nfirst + (t >> 6); n <= nlast; n += 8) {
                int o = offs[n], c = cnt[n];
                int lo = o - wb, hi = o + c - wb;
                int lo2 = lo > 0 ? lo : 0;
                int hi2 = hi < 256 ? hi : 256;
                if (lo2 >= hi2) continue;
                float m = 0.f;       // 0 floor matches zeros.at[].max
                for (int r = lo2; r < hi2; ++r)
                    m = fmaxf(m, bf2f(smem[r * XSTR + ch]));
                if (lo >= 0 && hi <= 256)
                    cf_bb[(size_t)n * HD + C0 + ch] = f2bf(m);
                else
                    atomicMax((int*)&cf_b32[(size_t)n * HD + C0 + ch], __float_as_int(m));
            }
            __syncthreads();
        }
    }
}

// ---------------------------------------------------------------------------
__global__ __launch_bounds__(256) void fixup(
    const int* __restrict__ offs, const int* __restrict__ cnt,
    const float* __restrict__ cf_b32, u16* __restrict__ cf_bb)
{
    const int n = blockIdx.x * 2 + (threadIdx.x >> 7);
    const int ch = threadIdx.x & 127;
    int o = offs[n], c = cnt[n];
    if (c > 0 && (o >> 8) != ((o + c - 1) >> 8))
        cf_bb[(size_t)n * HD + ch] = f2bf(cf_b32[(size_t)n * HD + ch]);
}

// ---------------------------------------------------------------------------
__global__ __launch_bounds__(128) void heads(
    const unsigned* __restrict__ ipf0_m,
    const float* __restrict__ ipf1, const float* __restrict__ ipf2,
    const float* __restrict__ secW, const float* __restrict__ secB,
    const unsigned* __restrict__ pg_m, const unsigned* __restrict__ sg_m,
    const float* __restrict__ geoW, const float* __restrict__ geoB,
    const float* __restrict__ gnw, const float* __restrict__ gnb,
    float* __restrict__ out)
{
    const int t = threadIdx.x;
    if (blockIdx.x == 0) {
        __shared__ float s[384];
        s[t]       = funmap(ipf0_m[t]);
        s[128 + t] = ipf1[t];
        s[256 + t] = ipf2[t];
        __syncthreads();
        float acc = secB[t];
        #pragma unroll 4
        for (int k = 0; k < 384; ++k) acc = fmaf(s[k], secW[t*384 + k], acc);
        out[t] = leaky(acc);
    } else {
        __shared__ float pg[128];
        __shared__ float tt[128];
        pg[t] = leaky(funmap(pg_m[t]));
        float sg = leaky(funmap(sg_m[t]));
        __syncthreads();
        float acc = geoB[t];
        #pragma unroll 4
        for (int k = 0; k < 128; ++k) acc = fmaf(pg[k], geoW[t*128 + k], acc);
        tt[t] = acc;
        __syncthreads();
        const int g = (t >> 3) << 3;
        float mu = 0.f, m2 = 0.f;
        #pragma unroll
        for (int q = 0; q < 8; ++q) { float x = tt[g + q]; mu += x; m2 += x*x; }
        mu *= 0.125f;
        m2 = m2 * 0.125f - mu * mu;
        float xn = (acc - mu) * rsqrtf(m2 + 1e-5f);
        out[128 + t] = leaky(sg + xn * gnw[t] + gnb[t]);
    }
}

// ---------------------------------------------------------------------------
extern "C" void kernel_launch(void* const* d_in, const int* in_sizes, int n_in,
                              void* d_out, int out_size, void* d_ws, size_t ws_size,
                              hipStream_t stream)
{
    const float* child_feats  = (const float*)d_in[0];
    const float* child_geo    = (const float*)d_in[1];
    const float* child_exists = (const float*)d_in[2];
    const float* etoh         = (const float*)d_in[3];
    const int*   eidx         = (const int*)  d_in[4];
    const float* op_w   = (const float*)d_in[5];
    const float* op_b   = (const float*)d_in[6];
    const float* sec_w  = (const float*)d_in[7];
    const float* sec_b  = (const float*)d_in[8];
    const float* edge_w = (const float*)d_in[9];
    const float* edge_b = (const float*)d_in[10];
    const float* geo_w  = (const float*)d_in[11];
    const float* geo_b  = (const float*)d_in[12];
    const float* sgeo_w = (const float*)d_in[13];
    const float* sgeo_b = (const float*)d_in[14];
    const float* gn_w   = (const float*)d_in[15];
    const float* gn_b   = (const float*)d_in[16];
    const float* skip_w = (const float*)d_in[17];
    const float* skip_b = (const float*)d_in[18];
    float* out = (float*)d_out;

    // workspace layout (all offsets 16B aligned)
    char* ws = (char*)d_ws;
    size_t off = 0;
    u16*   cf_a   = (u16*)(ws + off);   off += (size_t)N_NODES*HD*2;
    u16*   featsb = (u16*)(ws + off);   off += (size_t)N_NODES*KOP*2;
    u16*   geob   = (u16*)(ws + off);   off += (size_t)N_NODES*HD*2;
    u16*   Wb     = (u16*)(ws + off);   off += (size_t)2*128*KPAD*2;
    u16*   Wop    = (u16*)(ws + off);   off += (size_t)128*KOP*2;
    u16*   Wgeo   = (u16*)(ws + off);   off += (size_t)128*128*2;
    u16*   Wskip  = (u16*)(ws + off);   off += (size_t)128*128*2;
    int*   from_p = (int*)(ws + off);   off += (size_t)N_EDGES*4;
    int*   to_p   = (int*)(ws + off);   off += (size_t)N_EDGES*4;
    uint2* efb_p  = (uint2*)(ws + off); off += (size_t)N_EDGES*8;
    int*   offs   = (int*)(ws + off);   off += (size_t)N_NODES*4;
    char*  zero0  = ws + off;
    u16*   cf_bb  = (u16*)(ws + off);         off += (size_t)N_NODES*HD*2;
    float* cf_b32 = (float*)(ws + off);       off += (size_t)N_NODES*HD*4;
    unsigned* ipf0_m = (unsigned*)(ws + off); off += 128*4;
    float*    ipf1   = (float*)(ws + off);    off += 128*4;
    float*    ipf2   = (float*)(ws + off);    off += 128*4;
    unsigned* pg_m   = (unsigned*)(ws + off); off += 128*4;
    unsigned* sg_m   = (unsigned*)(ws + off); off += 128*4;
    int*      count  = (int*)(ws + off);      off += (size_t)N_NODES*4;
    int*      cursor = (int*)(ws + off);      off += (size_t)N_NODES*4;
    size_t zero_bytes = (size_t)(ws + off - zero0);

    hipMemsetAsync(zero0, 0, zero_bytes, stream);

    prep<<<PREP_GRID, 256, 0, stream>>>(
        edge_w, Wb, op_w, Wop, geo_w, Wgeo, skip_w, Wskip,
        child_feats, featsb, child_geo, geob, eidx, count);

    scan_offsets<<<1, 1024, 0, stream>>>(count, offs);

    // fill_perm + node GEMMs in one launch
    mid<<<1721, 256, 0, stream>>>(
        eidx, etoh, offs, cursor, from_p, to_p, efb_p,
        featsb, geob, child_exists, Wop, op_b, Wgeo, geo_b, Wskip, skip_b,
        cf_a, ipf0_m, pg_m, sg_m);

    // iter 1: column-split MFMA messages + fused in-LDS segment max
    edge_mfma<1><<<2 * (N_EDGES/512), 512, 0, stream>>>(
        cf_a, from_p, to_p, efb_p, Wb, edge_b,
        offs, count, cf_bb, cf_b32, (int*)ipf1);

    fixup<<<N_NODES/2, 256, 0, stream>>>(offs, count, cf_b32, cf_bb);

    // iter 2: only column max needed
    edge_mfma<0><<<2 * (N_EDGES/512), 512, 0, stream>>>(
        cf_bb, from_p, to_p, efb_p, Wb + 128*KPAD, edge_b + 128,
        offs, count, nullptr, nullptr, (int*)ipf2);

    heads<<<2, 128, 0, stream>>>(ipf0_m, ipf1, ipf2, sec_w, sec_b,
                                 pg_m, sg_m, sgeo_w, sgeo_b, gn_w, gn_b, out);
}